// Round 10
// baseline (195.746 us; speedup 1.0000x reference)
//
#include <hip/hip_runtime.h>
#include <math.h>

#define B_    2
#define NB_   512
#define C_    80
#define FEAT_ 1024
#define FN_   128
#define FC_   128
#define PE_   64
#define G_    16
#define DQ_   64
#define EO_   8
#define NT_   3
#define SCALE_CLAMP_ 4.135166556742356f

typedef __attribute__((ext_vector_type(8))) short bf16x8;
typedef __attribute__((ext_vector_type(4))) float f32x4;

// ---- workspace layout (float offsets) ----
#define O_ROIP    ((size_t)0)                                   // 2*1024*128 (K-half partials)
#define O_RANKP   (O_ROIP + (size_t)2*B_*NB_*FC_)               // 2*128*128
#define O_RANKIDX (O_RANKP + (size_t)2*FN_*FC_)                 // B*128*80 (int)
#define O_SSCORE  (O_RANKIDX + (size_t)B_*FN_*C_)               // B*128*80
#define O_SBOX    (O_SSCORE + (size_t)B_*FN_*C_)                // B*128*80*4
#define O_EMB     (O_SBOX + (size_t)B_*FN_*C_*4)                // B*128*80*128
#define O_ATT     (O_EMB + (size_t)B_*FN_*C_*FC_)               // B*128*80*128
#define O_LW      (O_ATT + (size_t)B_*FN_*C_*FC_)               // 2*80*128*16*128 f16 = 84MB (log w)
#define O_WT      (O_LW + (size_t)B_*C_*FN_*G_*FN_/2)           // 16*144*128 bf16
#define O_EMBB    (O_WT + (size_t)16*144*128/2)                 // B*128*80*128 bf16

__device__ __forceinline__ float bf2f(unsigned short u) {
    return __uint_as_float(((unsigned int)u) << 16);
}
__device__ __forceinline__ unsigned short f2bf(float f) {
    unsigned int x = __float_as_uint(f);
    unsigned int r = (x + 0x7fff + ((x >> 16) & 1)) >> 16;   // RNE
    return (unsigned short)r;
}
__device__ __forceinline__ unsigned short f2h(float x) {
    _Float16 h = (_Float16)x;
    return __builtin_bit_cast(unsigned short, h);
}
__device__ __forceinline__ float h2f(unsigned short u) {
    _Float16 h = __builtin_bit_cast(_Float16, u);
    return (float)h;
}

// 16B-granule swizzle, 128B row (8 granules)
#define ADDR128(row, gr)  ((row)*128 + ((((gr) ^ ((row)&7))) << 4))

// ============ prep: WT[g][144][128] bf16 (Wq^T | Wk^T | Wo^T | zeros) ============
__global__ __launch_bounds__(256) void k_prep(const float* __restrict__ q_w,
                                              const float* __restrict__ k_w,
                                              const float* __restrict__ out_w,
                                              unsigned short* __restrict__ wt)
{
    const int g = blockIdx.x;
    const int t = threadIdx.x;
    for (int idx = t; idx < 144*16; idx += 256) {
        const int row = idx >> 4;
        const int kc  = (idx & 15) * 8;
        unsigned short u[8];
        if (row < 64) {
            #pragma unroll
            for (int j = 0; j < 8; ++j) u[j] = f2bf(q_w[(size_t)(kc + j)*1024 + g*DQ_ + row]);
        } else if (row < 128) {
            const int r = row - 64;
            #pragma unroll
            for (int j = 0; j < 8; ++j) u[j] = f2bf(k_w[(size_t)(kc + j)*1024 + g*DQ_ + r]);
        } else if (row < 136) {
            const int e = row - 128;
            #pragma unroll
            for (int j = 0; j < 8; ++j) u[j] = f2bf(out_w[(size_t)g*FC_*EO_ + (size_t)(kc + j)*EO_ + e]);
        } else {
            #pragma unroll
            for (int j = 0; j < 8; ++j) u[j] = 0;
        }
        *(uint4*)(wt + (size_t)g*144*128 + row*128 + kc) =
            make_uint4((unsigned)u[0] | ((unsigned)u[1] << 16),
                       (unsigned)u[2] | ((unsigned)u[3] << 16),
                       (unsigned)u[4] | ((unsigned)u[5] << 16),
                       (unsigned)u[6] | ((unsigned)u[7] << 16));
    }
}

// ============ embed GEMMs: roi (row-tiles 0..63) + rank (64..71), x2 K-halves ============
__global__ __launch_bounds__(256) void k_embed(const float* __restrict__ roi_feat,
                                               const float* __restrict__ roi_w,
                                               const float* __restrict__ roi_b,
                                               const float* __restrict__ rank_w,
                                               const float* __restrict__ rank_b,
                                               float* __restrict__ roiP,
                                               float* __restrict__ rankP)
{
    const int bid = blockIdx.x;
    const int kh  = bid & 1;
    const int rt  = bid >> 1;            // 0..71
    const bool isRank = rt >= 64;
    const int row0 = (isRank ? rt - 64 : rt) * 16;
    const int t = threadIdx.x;
    const int w = t >> 6, lane = t & 63, lr = lane & 15, lh = lane >> 4;
    const int col0 = w * 32;
    const float* W = isRank ? rank_w : roi_w;
    const float* bias = isRank ? rank_b : roi_b;

    const int arow = row0 + lr;
    f32x4 acc0 = {0,0,0,0}, acc1 = {0,0,0,0};

    #pragma unroll 4
    for (int ks = 0; ks < 16; ++ks) {
        const int kb = kh*512 + ks*32 + lh*8;
        bf16x8 af;
        if (!isRank) {
            float4 a0 = *(const float4*)(roi_feat + (size_t)arow*FEAT_ + kb);
            float4 a1 = *(const float4*)(roi_feat + (size_t)arow*FEAT_ + kb + 4);
            af[0] = (short)f2bf(a0.x); af[1] = (short)f2bf(a0.y);
            af[2] = (short)f2bf(a0.z); af[3] = (short)f2bf(a0.w);
            af[4] = (short)f2bf(a1.x); af[5] = (short)f2bf(a1.y);
            af[6] = (short)f2bf(a1.z); af[7] = (short)f2bf(a1.w);
        } else {
            #pragma unroll
            for (int j = 0; j < 8; ++j) {
                int k = kb + j;
                int kk = k & 511;
                float inv = exp2f(-(float)kk * 0.0194644226f);  // log2(1000)/512
                float arg = (float)arow * inv;
                float v = (k < 512) ? __sinf(arg) : __cosf(arg);
                af[j] = (short)f2bf(v);
            }
        }
        bf16x8 bf0, bf1;
        #pragma unroll
        for (int j = 0; j < 8; ++j) {
            const float* wr = W + (size_t)(kb + j)*FC_ + col0 + lr;
            bf0[j] = (short)f2bf(wr[0]);
            bf1[j] = (short)f2bf(wr[16]);
        }
        acc0 = __builtin_amdgcn_mfma_f32_16x16x32_bf16(af, bf0, acc0, 0, 0, 0);
        acc1 = __builtin_amdgcn_mfma_f32_16x16x32_bf16(af, bf1, acc1, 0, 0, 0);
    }
    float* dst = isRank ? (rankP + (size_t)kh*FN_*FC_) : (roiP + (size_t)kh*(B_*NB_)*FC_);
    #pragma unroll
    for (int tile = 0; tile < 2; ++tile) {
        f32x4 a = tile ? acc1 : acc0;
        int col = col0 + tile*16 + lr;
        float bv = (kh == 0) ? bias[col] : 0.0f;
        #pragma unroll
        for (int reg = 0; reg < 4; ++reg) {
            int rr = row0 + lh*4 + reg;
            dst[(size_t)rr*FC_ + col] = a[reg] + bv;
        }
    }
}

// ============ softmax over boxes + stable top-128 rank ============
__global__ __launch_bounds__(512) void k_topk(const float* __restrict__ scores,
                                              int* __restrict__ rank_idx,
                                              float* __restrict__ sorted_score)
{
    int b = blockIdx.x / C_, c = blockIdx.x % C_;
    __shared__ float p[NB_];
    __shared__ float red[NB_];
    int i = threadIdx.x;
    float s = scores[(size_t)(b*NB_ + i)*(C_+1) + c];
    red[i] = s; __syncthreads();
    for (int o = 256; o > 0; o >>= 1) { if (i < o) red[i] = fmaxf(red[i], red[i+o]); __syncthreads(); }
    float mx = red[0]; __syncthreads();
    float e = expf(s - mx);
    red[i] = e; __syncthreads();
    for (int o = 256; o > 0; o >>= 1) { if (i < o) red[i] += red[i+o]; __syncthreads(); }
    float sum = red[0]; __syncthreads();
    float pi = e / sum;
    p[i] = pi; __syncthreads();
    int rank = 0;
    for (int j4 = 0; j4 < NB_/4; ++j4) {
        float4 pj = *(const float4*)&p[j4*4];
        int j = j4*4;
        rank += (pj.x > pi) || (pj.x == pi && (j+0) < i);
        rank += (pj.y > pi) || (pj.y == pi && (j+1) < i);
        rank += (pj.z > pi) || (pj.z == pi && (j+2) < i);
        rank += (pj.w > pi) || (pj.w == pi && (j+3) < i);
    }
    if (rank < FN_) {
        rank_idx[(size_t)(b*FN_ + rank)*C_ + c] = i;
        sorted_score[(size_t)(b*FN_ + rank)*C_ + c] = pi;
    }
}

// ============ gather emb_feat (+bf16 copy) + refined boxes ============
__global__ __launch_bounds__(256) void k_gather(const int* __restrict__ rank_idx,
                                                const float* __restrict__ roiP,
                                                const float* __restrict__ rankP,
                                                const float* __restrict__ pdeltas,
                                                const float* __restrict__ pboxes,
                                                float* __restrict__ emb_feat,
                                                unsigned short* __restrict__ embB,
                                                float* __restrict__ sorted_boxes)
{
    const int t = threadIdx.x;
    const int item = blockIdx.x*8 + (t >> 5);
    const int l = t & 31;
    const int c = item % C_;
    const int bn = item / C_;
    const int n = bn & (FN_-1);
    const int b = bn >> 7;
    const int idx = rank_idx[item];
    const int row = b*NB_ + idx;
    float4 e0 = *(const float4*)(roiP + (size_t)row*FC_ + l*4);
    float4 e1 = *(const float4*)(roiP + (size_t)(B_*NB_ + row)*FC_ + l*4);
    float4 r0 = *(const float4*)(rankP + (size_t)n*FC_ + l*4);
    float4 r1 = *(const float4*)(rankP + (size_t)(FN_ + n)*FC_ + l*4);
    float4 sm = make_float4(e0.x+e1.x+r0.x+r1.x, e0.y+e1.y+r0.y+r1.y,
                            e0.z+e1.z+r0.z+r1.z, e0.w+e1.w+r0.w+r1.w);
    *(float4*)(emb_feat + (size_t)item*FC_ + l*4) = sm;
    *(uint2*)(embB + (size_t)item*FC_ + l*4) =
        make_uint2((unsigned)f2bf(sm.x) | ((unsigned)f2bf(sm.y) << 16),
                   (unsigned)f2bf(sm.z) | ((unsigned)f2bf(sm.w) << 16));
    if (l == 0) {
        float x1 = pboxes[row*4+0], y1 = pboxes[row*4+1], x2 = pboxes[row*4+2], y2 = pboxes[row*4+3];
        float w = x2 - x1, h = y2 - y1;
        float cx = x1 + 0.5f*w, cy = y1 + 0.5f*h;
        const float* dl = pdeltas + (size_t)row*(C_*4) + c*4;
        float dx = dl[0]/10.0f, dy = dl[1]/10.0f;
        float dw = fminf(dl[2]/5.0f, SCALE_CLAMP_);
        float dh = fminf(dl[3]/5.0f, SCALE_CLAMP_);
        float pcx = dx*w + cx, pcy = dy*h + cy;
        float pw = expf(dw)*w, ph = expf(dh)*h;
        float* ob = sorted_boxes + (size_t)item*4;
        ob[0] = pcx - 0.5f*pw; ob[1] = pcy - 0.5f*ph;
        ob[2] = pcx + 0.5f*pw; ob[3] = pcy + 0.5f*ph;
    }
}

// ============ prior via MFMA -> store f16(log w) ============
// grid: B*C*64 (2 n per block, 256 pairs), 256 threads.
__global__ __launch_bounds__(256) void k_pos2(const float* __restrict__ sorted_boxes,
                                              const float* __restrict__ pos_w,
                                              const float* __restrict__ pos_b,
                                              unsigned short* __restrict__ lw)
{
    const int n2   = blockIdx.x & 63;
    const int rest = blockIdx.x >> 6;
    const int cl   = rest % C_;
    const int b    = rest / C_;
    const int n0   = n2 * 2;
    const int t    = threadIdx.x;

    __shared__ float geomL[FN_][6];               // 3 KB
    __shared__ unsigned short featL[256*PE_];     // 32 KB, swizzled 128B rows
    __shared__ unsigned short poswL[G_*PE_];      // 2 KB, swizzled 128B rows
    __shared__ float pbL[G_];
    __shared__ float sdimL[8];

    if (t < FN_) {
        const float* bx = sorted_boxes + (((size_t)(b*FN_ + t))*C_ + cl)*4;
        float x1 = bx[0], y1 = bx[1], x2 = bx[2], y2 = bx[3];
        float w = x2 - x1 + 1.0f;
        float h = y2 - y1 + 1.0f;
        geomL[t][0] = 0.5f*(x1+x2);
        geomL[t][1] = 0.5f*(y1+y2);
        geomL[t][2] = w;
        geomL[t][3] = h;
        geomL[t][4] = __logf(w);
        geomL[t][5] = __logf(h);
    } else {
        int id = t - 128;
        int g  = id >> 3;
        int gr = id & 7;
        unsigned short u[8];
        #pragma unroll
        for (int j = 0; j < 8; ++j) u[j] = f2bf(pos_w[(gr*8 + j)*G_ + g]);
        *(uint4*)((char*)poswL + ADDR128(g, gr)) =
            make_uint4((unsigned)u[0] | ((unsigned)u[1] << 16),
                       (unsigned)u[2] | ((unsigned)u[3] << 16),
                       (unsigned)u[4] | ((unsigned)u[5] << 16),
                       (unsigned)u[6] | ((unsigned)u[7] << 16));
    }
    if (t < G_) pbL[t] = pos_b[t];
    if (t >= 16 && t < 24) sdimL[t-16] = 1.0f / powf(1000.0f, 0.125f*(float)(t-16));
    __syncthreads();

    {
        const int nl = t >> 7;
        const int m  = t & 127;
        const int n  = n0 + nl;
        float pm[4];
        {
            float cxn = geomL[n][0], cyn = geomL[n][1];
            float rwn = 1.0f/geomL[n][2], rhn = 1.0f/geomL[n][3];
            pm[0] = __logf(fmaxf(fabsf((cxn - geomL[m][0]) * rwn), 1e-3f)) * 100.0f;
            pm[1] = __logf(fmaxf(fabsf((cyn - geomL[m][1]) * rhn), 1e-3f)) * 100.0f;
            pm[2] = (geomL[n][4] - geomL[m][4]) * 100.0f;
            pm[3] = (geomL[n][5] - geomL[m][5]) * 100.0f;
        }
        char* base = (char*)featL;
        #pragma unroll
        for (int f = 0; f < 4; ++f) {
            float s[8], c[8];
            #pragma unroll
            for (int r = 0; r < 8; ++r) {
                __sincosf(pm[f] * sdimL[r], &s[r], &c[r]);
            }
            unsigned short us[8], uc[8];
            #pragma unroll
            for (int r = 0; r < 8; ++r) { us[r] = f2bf(s[r]); uc[r] = f2bf(c[r]); }
            *(uint4*)(base + ADDR128(t, 2*f)) =
                make_uint4((unsigned)us[0] | ((unsigned)us[1] << 16),
                           (unsigned)us[2] | ((unsigned)us[3] << 16),
                           (unsigned)us[4] | ((unsigned)us[5] << 16),
                           (unsigned)us[6] | ((unsigned)us[7] << 16));
            *(uint4*)(base + ADDR128(t, 2*f + 1)) =
                make_uint4((unsigned)uc[0] | ((unsigned)uc[1] << 16),
                           (unsigned)uc[2] | ((unsigned)uc[3] << 16),
                           (unsigned)uc[4] | ((unsigned)uc[5] << 16),
                           (unsigned)uc[6] | ((unsigned)uc[7] << 16));
        }
    }
    __syncthreads();

    {
        const int wave = t >> 6, lane = t & 63;
        const int lr = lane & 15, lh = lane >> 4;
        const float pbg = pbL[lr];           // g = lr
        #pragma unroll
        for (int ti = 0; ti < 4; ++ti) {
            const int t16 = wave*4 + ti;
            f32x4 acc = {0,0,0,0};
            #pragma unroll
            for (int ks = 0; ks < 2; ++ks) {
                bf16x8 a  = *(const bf16x8*)((char*)featL + ADDR128(t16*16 + lr, ks*4 + lh));
                bf16x8 bb = *(const bf16x8*)((char*)poswL + ADDR128(lr, ks*4 + lh));
                acc = __builtin_amdgcn_mfma_f32_16x16x32_bf16(a, bb, acc, 0, 0, 0);
            }
            const int g = lr;
            #pragma unroll
            for (int reg = 0; reg < 4; ++reg) {
                int p = t16*16 + lh*4 + reg;
                int n = n0 + (p >> 7);
                int m = p & 127;
                float w = fmaxf(fmaxf(acc[reg] + pbg, 0.0f), 1e-6f);
                lw[(((size_t)(b*C_ + cl)*FN_ + n)*G_ + g)*FN_ + m] = f2h(__logf(w));
            }
        }
    }
}

// ============ MFMA attention per (batch, class, group) — 70.5 KB LDS ============
// region FT (34816 B, rows stride 272B): ft bf16 -> aff f16 -> P bf16
#define FT_OFF   0
#define QL_OFF   34816    // q bf16 [128n][64dq] swz 16 KB
#define KL_OFF   51200    // k bf16 [128m][64dq] swz 16 KB
#define VT_OFF   67584    // V'^T bf16 [16e][128m] swz 4 KB
#define BIAS_OFF 71680    // 128 f32
#define SMEM_SZ  72192

__global__ __launch_bounds__(1024, 8) void k_attn(const unsigned short* __restrict__ embB,
                                               const unsigned short* __restrict__ wt,
                                               const float* __restrict__ q_b,
                                               const float* __restrict__ k_b,
                                               const float* __restrict__ out_b,
                                               const unsigned short* __restrict__ lw,
                                               float* __restrict__ att)
{
    const int g    = blockIdx.x & 15;
    const int rest = blockIdx.x >> 4;
    const int cl   = rest % C_;
    const int b    = rest / C_;
    const int c    = cl;
    const int t  = threadIdx.x;
    const int wave = t >> 6;
    const int lane = t & 63;
    const int lr = lane & 15;
    const int lh = lane >> 4;              // 0..3

    __shared__ char smem[SMEM_SZ];
    float* biasL = (float*)(smem + BIAS_OFF);

    // ================= P0: staging (ft copy bf16 + VT-zero + bias) =================
    {
        const char* src = (const char*)embB + ((size_t)(b*FN_)*C_ + c)*FC_*2;
        #pragma unroll
        for (int s = 0; s < 2; ++s) {
            int fi = t + s*1024;
            int n  = fi >> 4;
            int o16 = (fi & 15) * 16;
            uint4 v = *(const uint4*)(src + (size_t)n*C_*FC_*2 + o16);
            *(uint4*)(smem + FT_OFF + n*272 + o16) = v;
        }
    }
    if (t >= 512 && t < 768) {
        int i = t - 512;
        *(uint2*)(smem + VT_OFF + 8*256 + i*8) = make_uint2(0u, 0u);
    }
    if (t >= 128 && t < 256) {
        int r = t - 128;
        biasL[r] = (r < 64) ? q_b[g*DQ_ + r] : k_b[g*DQ_ + (r-64)];
    }
    __syncthreads();

    // ================= P1: proj MFMA (A from pre-transposed bf16 WT) =================
    {
        const int rb = (wave >> 2) * 32;
        const int nb = (wave & 3) * 32;
        const char* wtg = (const char*)wt + (size_t)g*144*256;
        f32x4 acc00 = {0,0,0,0}, acc01 = {0,0,0,0}, acc10 = {0,0,0,0}, acc11 = {0,0,0,0};
        f32x4 accV  = {0,0,0,0};
        #pragma unroll
        for (int ks = 0; ks < 4; ++ks) {
            const int fo = ks*64 + lh*16;
            bf16x8 a0 = *(const bf16x8*)(wtg + (rb + lr)*256 + fo);
            bf16x8 a1 = *(const bf16x8*)(wtg + (rb + 16 + lr)*256 + fo);
            bf16x8 b0 = *(const bf16x8*)(smem + FT_OFF + (nb + lr)*272 + fo);
            bf16x8 b1 = *(const bf16x8*)(smem + FT_OFF + (nb + 16 + lr)*272 + fo);
            acc00 = __builtin_amdgcn_mfma_f32_16x16x32_bf16(a0, b0, acc00, 0, 0, 0);
            acc01 = __builtin_amdgcn_mfma_f32_16x16x32_bf16(a0, b1, acc01, 0, 0, 0);
            acc10 = __builtin_amdgcn_mfma_f32_16x16x32_bf16(a1, b0, acc10, 0, 0, 0);
            acc11 = __builtin_amdgcn_mfma_f32_16x16x32_bf16(a1, b1, acc11, 0, 0, 0);
            if (wave < 8) {
                bf16x8 av = *(const bf16x8*)(wtg + (128 + lr)*256 + fo);
                bf16x8 bv = *(const bf16x8*)(smem + FT_OFF + (wave*16 + lr)*272 + fo);
                accV = __builtin_amdgcn_mfma_f32_16x16x32_bf16(av, bv, accV, 0, 0, 0);
            }
        }
        #pragma unroll
        for (int ti = 0; ti < 2; ++ti) {
            #pragma unroll
            for (int tj = 0; tj < 2; ++tj) {
                f32x4 a = (ti == 0) ? (tj == 0 ? acc00 : acc01) : (tj == 0 ? acc10 : acc11);
                int r0 = rb + ti*16 + lh*4;
                int n  = nb + tj*16 + lr;
                float v0 = a[0] + biasL[r0+0];
                float v1 = a[1] + biasL[r0+1];
                float v2 = a[2] + biasL[r0+2];
                float v3 = a[3] + biasL[r0+3];
                int dq0 = r0 & 63;
                int off = (r0 < 64 ? QL_OFF : KL_OFF);
                char* dst = smem + off + ADDR128(n, dq0 >> 3) + ((dq0 >> 2) & 1)*8;
                *(uint2*)dst = make_uint2((unsigned)f2bf(v0) | ((unsigned)f2bf(v1) << 16),
                                          (unsigned)f2bf(v2) | ((unsigned)f2bf(v3) << 16));
            }
        }
        if (wave < 8 && lh < 2) {
            int m = wave*16 + lr;
            #pragma unroll
            for (int reg = 0; reg < 4; ++reg) {
                int e = lh*4 + reg;
                char* dst = smem + VT_OFF + (e)*256 + ((((m >> 3) ^ e)) << 4) + (m & 7)*2;
                *(unsigned short*)dst = f2bf(accV[reg]);
            }
        }
    }
    __syncthreads();

    // ================= P2: aff MFMA -> f16 into FT region (ft is dead) =================
    {
        const int nb = (wave >> 2) * 32;
        const int mb = (wave & 3) * 32;
        f32x4 acc00 = {0,0,0,0}, acc01 = {0,0,0,0}, acc10 = {0,0,0,0}, acc11 = {0,0,0,0};
        #pragma unroll
        for (int ks = 0; ks < 2; ++ks) {
            int soff = ((ks*4 + lh) ^ (lr & 7)) << 4;
            bf16x8 a0 = *(const bf16x8*)(smem + QL_OFF + (nb + lr)*128 + soff);
            bf16x8 a1 = *(const bf16x8*)(smem + QL_OFF + (nb + 16 + lr)*128 + soff);
            bf16x8 b0 = *(const bf16x8*)(smem + KL_OFF + (mb + lr)*128 + soff);
            bf16x8 b1 = *(const bf16x8*)(smem + KL_OFF + (mb + 16 + lr)*128 + soff);
            acc00 = __builtin_amdgcn_mfma_f32_16x16x32_bf16(a0, b0, acc00, 0, 0, 0);
            acc01 = __builtin_amdgcn_mfma_f32_16x16x32_bf16(a0, b1, acc01, 0, 0, 0);
            acc10 = __builtin_amdgcn_mfma_f32_16x16x32_bf16(a1, b0, acc10, 0, 0, 0);
            acc11 = __builtin_amdgcn_mfma_f32_16x16x32_bf16(a1, b1, acc11, 0, 0, 0);
        }
        #pragma unroll
        for (int ti = 0; ti < 2; ++ti) {
            #pragma unroll
            for (int tj = 0; tj < 2; ++tj) {
                f32x4 a = (ti == 0) ? (tj == 0 ? acc00 : acc01) : (tj == 0 ? acc10 : acc11);
                int n0 = nb + ti*16 + lh*4;
                int m  = mb + tj*16 + lr;
                #pragma unroll
                for (int reg = 0; reg < 4; ++reg)
                    *(unsigned short*)(smem + FT_OFF + (n0 + reg)*272 + 2*m) = f2h(a[reg]);
            }
        }
    }
    __syncthreads();

    // ================= P3: softmax (aff f16 + lw f16, vectorized) -> P bf16 in place =================
    {
        const int row = t >> 3;
        const int lp  = t & 7;
        const int m0  = lp * 16;
        const unsigned short* lwrow = lw + ((((size_t)(b*C_ + cl))*FN_ + row)*G_ + g)*FN_ + m0;
        uint4 gl0 = *(const uint4*)(lwrow);
        uint4 gl1 = *(const uint4*)(lwrow + 8);
        char* abase = smem + FT_OFF + row*272 + lp*32;
        uint4 af0 = *(const uint4*)abase;
        uint4 af1 = *(const uint4*)(abase + 16);
        const unsigned short* ah0 = (const unsigned short*)&af0;
        const unsigned short* ah1 = (const unsigned short*)&af1;
        const unsigned short* lp0 = (const unsigned short*)&gl0;
        const unsigned short* lp1 = (const unsigned short*)&gl1;
        float v[16];
        float mx = -INFINITY;
        #pragma unroll
        for (int j = 0; j < 8; ++j) {
            float val = h2f(ah0[j])*0.125f + h2f(lp0[j]);
            v[j] = val; mx = fmaxf(mx, val);
        }
        #pragma unroll
        for (int j = 0; j < 8; ++j) {
            float val = h2f(ah1[j])*0.125f + h2f(lp1[j]);
            v[8+j] = val; mx = fmaxf(mx, val);
        }
        #pragma unroll
        for (int s = 1; s < 8; s <<= 1) mx = fmaxf(mx, __shfl_xor(mx, s, 8));
        float sum = 0.f;
        #pragma unroll
        for (int j = 0; j < 16; ++j) { v[j] = __expf(v[j] - mx); sum += v[j]; }
        #pragma unroll
        for (int s = 1; s < 8; s <<= 1) sum += __shfl_xor(sum, s, 8);
        float rs = 1.0f / sum;
        unsigned short u[16];
        #pragma unroll
        for (int j = 0; j < 16; ++j) u[j] = f2bf(v[j] * rs);
        *(uint4*)abase = make_uint4((unsigned)u[0] | ((unsigned)u[1] << 16),
                                    (unsigned)u[2] | ((unsigned)u[3] << 16),
                                    (unsigned)u[4] | ((unsigned)u[5] << 16),
                                    (unsigned)u[6] | ((unsigned)u[7] << 16));
        *(uint4*)(abase + 16) = make_uint4((unsigned)u[8]  | ((unsigned)u[9]  << 16),
                                           (unsigned)u[10] | ((unsigned)u[11] << 16),
                                           (unsigned)u[12] | ((unsigned)u[13] << 16),
                                           (unsigned)u[14] | ((unsigned)u[15] << 16));
    }
    __syncthreads();

    // ================= P4: att = P @ V' =================
    if (wave < 8) {
        const int tb = wave * 16;
        f32x4 acc = {0,0,0,0};
        #pragma unroll
        for (int ks = 0; ks < 4; ++ks) {
            const int fo = ks*64 + lh*16;
            int soff = ((ks*4 + lh) ^ lr) << 4;
            bf16x8 a = *(const bf16x8*)(smem + FT_OFF + (tb + lr)*272 + fo);
            bf16x8 bv = *(const bf16x8*)(smem + VT_OFF + lr*256 + soff);
            acc = __builtin_amdgcn_mfma_f32_16x16x32_bf16(a, bv, acc, 0, 0, 0);
        }
        if (lr < 8) {
            float ob = out_b[g*EO_ + lr];
            #pragma unroll
            for (int reg = 0; reg < 4; ++reg) {
                int n = tb + lh*4 + reg;
                att[((size_t)(b*FN_ + n)*C_ + c)*FC_ + g*EO_ + lr] = acc[reg] + ob;
            }
        }
    }
}

// ============ final: 8 items/block, 32 lanes/item ============
__global__ __launch_bounds__(256) void k_final(const float* __restrict__ emb_feat,
                                               const float* __restrict__ att,
                                               const float* __restrict__ logit_w,
                                               const float* __restrict__ logit_b,
                                               const float* __restrict__ sorted_score,
                                               float* __restrict__ out)
{
    __shared__ float lwL[FC_*NT_ + NT_];
    const int t = threadIdx.x;
    for (int i = t; i < FC_*NT_ + NT_; i += 256)
        lwL[i] = (i < FC_*NT_) ? logit_w[i] : logit_b[i - FC_*NT_];
    __syncthreads();
    const int item = blockIdx.x*8 + (t >> 5);
    const int l = t & 31;
    const int d0 = l*4;
    float4 ev = *(const float4*)(emb_feat + (size_t)item*FC_ + d0);
    float4 av = *(const float4*)(att + (size_t)item*FC_ + d0);
    float a0 = fmaxf(ev.x + av.x, 0.f);
    float a1 = fmaxf(ev.y + av.y, 0.f);
    float a2 = fmaxf(ev.z + av.z, 0.f);
    float a3 = fmaxf(ev.w + av.w, 0.f);
    float s0 = a0*lwL[(d0+0)*NT_+0] + a1*lwL[(d0+1)*NT_+0] + a2*lwL[(d0+2)*NT_+0] + a3*lwL[(d0+3)*NT_+0];
    float s1 = a0*lwL[(d0+0)*NT_+1] + a1*lwL[(d0+1)*NT_+1] + a2*lwL[(d0+2)*NT_+1] + a3*lwL[(d0+3)*NT_+1];
    float s2 = a0*lwL[(d0+0)*NT_+2] + a1*lwL[(d0+1)*NT_+2] + a2*lwL[(d0+2)*NT_+2] + a3*lwL[(d0+3)*NT_+2];
    #pragma unroll
    for (int s = 1; s < 32; s <<= 1) {
        s0 += __shfl_xor(s0, s, 32);
        s1 += __shfl_xor(s1, s, 32);
        s2 += __shfl_xor(s2, s, 32);
    }
    if (l < NT_) {
        float lg = (l == 0) ? s0 : (l == 1) ? s1 : s2;
        lg += lwL[FC_*NT_ + l];
        float sg = 1.f / (1.f + expf(-lg));
        out[(size_t)item*NT_ + l] = sg * sorted_score[item];
    }
}

extern "C" void kernel_launch(void* const* d_in, const int* in_sizes, int n_in,
                              void* d_out, int out_size, void* d_ws, size_t ws_size,
                              hipStream_t stream) {
    (void)in_sizes; (void)n_in; (void)out_size; (void)ws_size;
    const float* roi_feat = (const float*)d_in[0];
    const float* scores   = (const float*)d_in[1];
    const float* pdeltas  = (const float*)d_in[2];
    const float* pboxes   = (const float*)d_in[3];
    const float* roi_w    = (const float*)d_in[4];
    const float* roi_b    = (const float*)d_in[5];
    const float* rank_w   = (const float*)d_in[6];
    const float* rank_b   = (const float*)d_in[7];
    const float* logit_w  = (const float*)d_in[8];
    const float* logit_b  = (const float*)d_in[9];
    const float* pos_w    = (const float*)d_in[10];
    const float* pos_b    = (const float*)d_in[11];
    const float* q_w      = (const float*)d_in[12];
    const float* q_b      = (const float*)d_in[13];
    const float* k_w      = (const float*)d_in[14];
    const float* k_b      = (const float*)d_in[15];
    const float* out_w    = (const float*)d_in[16];
    const float* out_b    = (const float*)d_in[17];
    float* ws = (float*)d_ws;

    float* roiP         = ws + O_ROIP;
    float* rankP        = ws + O_RANKP;
    int*   rank_idx     = (int*)(ws + O_RANKIDX);
    float* sorted_score = ws + O_SSCORE;
    float* sorted_boxes = ws + O_SBOX;
    float* emb_feat     = ws + O_EMB;
    float* att          = ws + O_ATT;
    unsigned short* lwb = (unsigned short*)(ws + O_LW);
    unsigned short* wtb = (unsigned short*)(ws + O_WT);
    unsigned short* embB = (unsigned short*)(ws + O_EMBB);

    k_prep<<<dim3(G_), dim3(256), 0, stream>>>(q_w, k_w, out_w, wtb);
    k_embed<<<dim3(144), dim3(256), 0, stream>>>(roi_feat, roi_w, roi_b, rank_w, rank_b,
                                                 roiP, rankP);
    k_topk<<<dim3(B_*C_), dim3(512), 0, stream>>>(scores, rank_idx, sorted_score);
    k_gather<<<dim3(B_*FN_*C_/8), dim3(256), 0, stream>>>(rank_idx, roiP, rankP,
                                                          pdeltas, pboxes, emb_feat, embB, sorted_boxes);
    k_pos2<<<dim3(B_*C_*64), dim3(256), 0, stream>>>(sorted_boxes, pos_w, pos_b, lwb);
    k_attn<<<dim3(B_*C_*G_), dim3(1024), 0, stream>>>(embB, wtb, q_b, k_b, out_b, lwb, att);
    k_final<<<dim3(B_*FN_*C_/8), dim3(256), 0, stream>>>(emb_feat, att, logit_w, logit_b,
                                                         sorted_score, d_out ? (float*)d_out : nullptr);
}

// Round 11
// 194.708 us; speedup vs baseline: 1.0053x; 1.0053x over previous
//
#include <hip/hip_runtime.h>
#include <math.h>

#define B_    2
#define NB_   512
#define C_    80
#define FEAT_ 1024
#define FN_   128
#define FC_   128
#define PE_   64
#define G_    16
#define DQ_   64
#define EO_   8
#define NT_   3
#define SCALE_CLAMP_ 4.135166556742356f

typedef __attribute__((ext_vector_type(8))) short bf16x8;
typedef __attribute__((ext_vector_type(4))) float f32x4;

// ---- workspace layout (float offsets) ----
#define O_ROIP    ((size_t)0)                                   // 2*1024*128 (K-half partials)
#define O_RANKP   (O_ROIP + (size_t)2*B_*NB_*FC_)               // 2*128*128
#define O_RANKIDX (O_RANKP + (size_t)2*FN_*FC_)                 // B*128*80 (int)
#define O_SSCORE  (O_RANKIDX + (size_t)B_*FN_*C_)               // B*128*80
#define O_SBOX    (O_SSCORE + (size_t)B_*FN_*C_)                // B*128*80*4
#define O_EMB     (O_SBOX + (size_t)B_*FN_*C_*4)                // B*128*80*128
#define O_ATT     (O_EMB + (size_t)B_*FN_*C_*FC_)               // B*128*80*128
#define O_LW      (O_ATT + (size_t)B_*FN_*C_*FC_)               // 2*80*128*16*128 f16 = 84MB (log w)
#define O_WT      (O_LW + (size_t)B_*C_*FN_*G_*FN_/2)           // 16*144*128 bf16
#define O_EMBB    (O_WT + (size_t)16*144*128/2)                 // B*128*80*128 bf16

__device__ __forceinline__ float bf2f(unsigned short u) {
    return __uint_as_float(((unsigned int)u) << 16);
}
__device__ __forceinline__ unsigned short f2bf(float f) {
    unsigned int x = __float_as_uint(f);
    unsigned int r = (x + 0x7fff + ((x >> 16) & 1)) >> 16;   // RNE
    return (unsigned short)r;
}
__device__ __forceinline__ unsigned short f2h(float x) {
    _Float16 h = (_Float16)x;
    return __builtin_bit_cast(unsigned short, h);
}
__device__ __forceinline__ float h2f(unsigned short u) {
    _Float16 h = __builtin_bit_cast(_Float16, u);
    return (float)h;
}

// 16B-granule swizzle, 128B row (8 granules)
#define ADDR128(row, gr)  ((row)*128 + ((((gr) ^ ((row)&7))) << 4))

// ============ embed GEMMs (blocks 0..143) + WT prep (blocks 144..159) ============
__global__ __launch_bounds__(256) void k_embed(const float* __restrict__ roi_feat,
                                               const float* __restrict__ roi_w,
                                               const float* __restrict__ roi_b,
                                               const float* __restrict__ rank_w,
                                               const float* __restrict__ rank_b,
                                               const float* __restrict__ q_w,
                                               const float* __restrict__ k_w,
                                               const float* __restrict__ out_w,
                                               float* __restrict__ roiP,
                                               float* __restrict__ rankP,
                                               unsigned short* __restrict__ wtg)
{
    const int bid = blockIdx.x;
    const int t = threadIdx.x;
    if (bid >= 144) {
        // ---- WT prep: WT[g][144][128] bf16 (Wq^T | Wk^T | Wo^T | zeros)
        const int g = bid - 144;
        for (int idx = t; idx < 144*16; idx += 256) {
            const int row = idx >> 4;
            const int kc  = (idx & 15) * 8;
            unsigned short u[8];
            if (row < 64) {
                #pragma unroll
                for (int j = 0; j < 8; ++j) u[j] = f2bf(q_w[(size_t)(kc + j)*1024 + g*DQ_ + row]);
            } else if (row < 128) {
                const int r = row - 64;
                #pragma unroll
                for (int j = 0; j < 8; ++j) u[j] = f2bf(k_w[(size_t)(kc + j)*1024 + g*DQ_ + r]);
            } else if (row < 136) {
                const int e = row - 128;
                #pragma unroll
                for (int j = 0; j < 8; ++j) u[j] = f2bf(out_w[(size_t)g*FC_*EO_ + (size_t)(kc + j)*EO_ + e]);
            } else {
                #pragma unroll
                for (int j = 0; j < 8; ++j) u[j] = 0;
            }
            *(uint4*)(wtg + (size_t)g*144*128 + row*128 + kc) =
                make_uint4((unsigned)u[0] | ((unsigned)u[1] << 16),
                           (unsigned)u[2] | ((unsigned)u[3] << 16),
                           (unsigned)u[4] | ((unsigned)u[5] << 16),
                           (unsigned)u[6] | ((unsigned)u[7] << 16));
        }
        return;
    }
    const int kh  = bid & 1;
    const int rt  = bid >> 1;            // 0..71
    const bool isRank = rt >= 64;
    const int row0 = (isRank ? rt - 64 : rt) * 16;
    const int w = t >> 6, lane = t & 63, lr = lane & 15, lh = lane >> 4;
    const int col0 = w * 32;
    const float* W = isRank ? rank_w : roi_w;
    const float* bias = isRank ? rank_b : roi_b;

    const int arow = row0 + lr;
    f32x4 acc0 = {0,0,0,0}, acc1 = {0,0,0,0};

    #pragma unroll 4
    for (int ks = 0; ks < 16; ++ks) {
        const int kb = kh*512 + ks*32 + lh*8;
        bf16x8 af;
        if (!isRank) {
            float4 a0 = *(const float4*)(roi_feat + (size_t)arow*FEAT_ + kb);
            float4 a1 = *(const float4*)(roi_feat + (size_t)arow*FEAT_ + kb + 4);
            af[0] = (short)f2bf(a0.x); af[1] = (short)f2bf(a0.y);
            af[2] = (short)f2bf(a0.z); af[3] = (short)f2bf(a0.w);
            af[4] = (short)f2bf(a1.x); af[5] = (short)f2bf(a1.y);
            af[6] = (short)f2bf(a1.z); af[7] = (short)f2bf(a1.w);
        } else {
            #pragma unroll
            for (int j = 0; j < 8; ++j) {
                int k = kb + j;
                int kk = k & 511;
                float inv = exp2f(-(float)kk * 0.0194644226f);  // log2(1000)/512
                float arg = (float)arow * inv;
                float v = (k < 512) ? __sinf(arg) : __cosf(arg);
                af[j] = (short)f2bf(v);
            }
        }
        bf16x8 bf0, bf1;
        #pragma unroll
        for (int j = 0; j < 8; ++j) {
            const float* wr = W + (size_t)(kb + j)*FC_ + col0 + lr;
            bf0[j] = (short)f2bf(wr[0]);
            bf1[j] = (short)f2bf(wr[16]);
        }
        acc0 = __builtin_amdgcn_mfma_f32_16x16x32_bf16(af, bf0, acc0, 0, 0, 0);
        acc1 = __builtin_amdgcn_mfma_f32_16x16x32_bf16(af, bf1, acc1, 0, 0, 0);
    }
    float* dst = isRank ? (rankP + (size_t)kh*FN_*FC_) : (roiP + (size_t)kh*(B_*NB_)*FC_);
    #pragma unroll
    for (int tile = 0; tile < 2; ++tile) {
        f32x4 a = tile ? acc1 : acc0;
        int col = col0 + tile*16 + lr;
        float bv = (kh == 0) ? bias[col] : 0.0f;
        #pragma unroll
        for (int reg = 0; reg < 4; ++reg) {
            int rr = row0 + lh*4 + reg;
            dst[(size_t)rr*FC_ + col] = a[reg] + bv;
        }
    }
}

// ============ softmax over boxes + stable top-128 rank ============
__global__ __launch_bounds__(512) void k_topk(const float* __restrict__ scores,
                                              int* __restrict__ rank_idx,
                                              float* __restrict__ sorted_score)
{
    int b = blockIdx.x / C_, c = blockIdx.x % C_;
    __shared__ float p[NB_];
    __shared__ float red[NB_];
    int i = threadIdx.x;
    float s = scores[(size_t)(b*NB_ + i)*(C_+1) + c];
    red[i] = s; __syncthreads();
    for (int o = 256; o > 0; o >>= 1) { if (i < o) red[i] = fmaxf(red[i], red[i+o]); __syncthreads(); }
    float mx = red[0]; __syncthreads();
    float e = expf(s - mx);
    red[i] = e; __syncthreads();
    for (int o = 256; o > 0; o >>= 1) { if (i < o) red[i] += red[i+o]; __syncthreads(); }
    float sum = red[0]; __syncthreads();
    float pi = e / sum;
    p[i] = pi; __syncthreads();
    int rank = 0;
    for (int j4 = 0; j4 < NB_/4; ++j4) {
        float4 pj = *(const float4*)&p[j4*4];
        int j = j4*4;
        rank += (pj.x > pi) || (pj.x == pi && (j+0) < i);
        rank += (pj.y > pi) || (pj.y == pi && (j+1) < i);
        rank += (pj.z > pi) || (pj.z == pi && (j+2) < i);
        rank += (pj.w > pi) || (pj.w == pi && (j+3) < i);
    }
    if (rank < FN_) {
        rank_idx[(size_t)(b*FN_ + rank)*C_ + c] = i;
        sorted_score[(size_t)(b*FN_ + rank)*C_ + c] = pi;
    }
}

// ============ gather emb_feat (+bf16 copy) + refined boxes ============
__global__ __launch_bounds__(256) void k_gather(const int* __restrict__ rank_idx,
                                                const float* __restrict__ roiP,
                                                const float* __restrict__ rankP,
                                                const float* __restrict__ pdeltas,
                                                const float* __restrict__ pboxes,
                                                float* __restrict__ emb_feat,
                                                unsigned short* __restrict__ embB,
                                                float* __restrict__ sorted_boxes)
{
    const int t = threadIdx.x;
    const int item = blockIdx.x*8 + (t >> 5);
    const int l = t & 31;
    const int c = item % C_;
    const int bn = item / C_;
    const int n = bn & (FN_-1);
    const int b = bn >> 7;
    const int idx = rank_idx[item];
    const int row = b*NB_ + idx;
    float4 e0 = *(const float4*)(roiP + (size_t)row*FC_ + l*4);
    float4 e1 = *(const float4*)(roiP + (size_t)(B_*NB_ + row)*FC_ + l*4);
    float4 r0 = *(const float4*)(rankP + (size_t)n*FC_ + l*4);
    float4 r1 = *(const float4*)(rankP + (size_t)(FN_ + n)*FC_ + l*4);
    float4 sm = make_float4(e0.x+e1.x+r0.x+r1.x, e0.y+e1.y+r0.y+r1.y,
                            e0.z+e1.z+r0.z+r1.z, e0.w+e1.w+r0.w+r1.w);
    *(float4*)(emb_feat + (size_t)item*FC_ + l*4) = sm;
    *(uint2*)(embB + (size_t)item*FC_ + l*4) =
        make_uint2((unsigned)f2bf(sm.x) | ((unsigned)f2bf(sm.y) << 16),
                   (unsigned)f2bf(sm.z) | ((unsigned)f2bf(sm.w) << 16));
    if (l == 0) {
        float x1 = pboxes[row*4+0], y1 = pboxes[row*4+1], x2 = pboxes[row*4+2], y2 = pboxes[row*4+3];
        float w = x2 - x1, h = y2 - y1;
        float cx = x1 + 0.5f*w, cy = y1 + 0.5f*h;
        const float* dl = pdeltas + (size_t)row*(C_*4) + c*4;
        float dx = dl[0]/10.0f, dy = dl[1]/10.0f;
        float dw = fminf(dl[2]/5.0f, SCALE_CLAMP_);
        float dh = fminf(dl[3]/5.0f, SCALE_CLAMP_);
        float pcx = dx*w + cx, pcy = dy*h + cy;
        float pw = expf(dw)*w, ph = expf(dh)*h;
        float* ob = sorted_boxes + (size_t)item*4;
        ob[0] = pcx - 0.5f*pw; ob[1] = pcy - 0.5f*ph;
        ob[2] = pcx + 0.5f*pw; ob[3] = pcy + 0.5f*ph;
    }
}

// ============ prior via MFMA -> store f16(log w) ============
__global__ __launch_bounds__(256) void k_pos2(const float* __restrict__ sorted_boxes,
                                              const float* __restrict__ pos_w,
                                              const float* __restrict__ pos_b,
                                              unsigned short* __restrict__ lw)
{
    const int n2   = blockIdx.x & 63;
    const int rest = blockIdx.x >> 6;
    const int cl   = rest % C_;
    const int b    = rest / C_;
    const int n0   = n2 * 2;
    const int t    = threadIdx.x;

    __shared__ float geomL[FN_][6];               // 3 KB
    __shared__ unsigned short featL[256*PE_];     // 32 KB, swizzled 128B rows
    __shared__ unsigned short poswL[G_*PE_];      // 2 KB, swizzled 128B rows
    __shared__ float pbL[G_];
    __shared__ float sdimL[8];

    if (t < FN_) {
        const float* bx = sorted_boxes + (((size_t)(b*FN_ + t))*C_ + cl)*4;
        float x1 = bx[0], y1 = bx[1], x2 = bx[2], y2 = bx[3];
        float w = x2 - x1 + 1.0f;
        float h = y2 - y1 + 1.0f;
        geomL[t][0] = 0.5f*(x1+x2);
        geomL[t][1] = 0.5f*(y1+y2);
        geomL[t][2] = w;
        geomL[t][3] = h;
        geomL[t][4] = __logf(w);
        geomL[t][5] = __logf(h);
    } else {
        int id = t - 128;
        int g  = id >> 3;
        int gr = id & 7;
        unsigned short u[8];
        #pragma unroll
        for (int j = 0; j < 8; ++j) u[j] = f2bf(pos_w[(gr*8 + j)*G_ + g]);
        *(uint4*)((char*)poswL + ADDR128(g, gr)) =
            make_uint4((unsigned)u[0] | ((unsigned)u[1] << 16),
                       (unsigned)u[2] | ((unsigned)u[3] << 16),
                       (unsigned)u[4] | ((unsigned)u[5] << 16),
                       (unsigned)u[6] | ((unsigned)u[7] << 16));
    }
    if (t < G_) pbL[t] = pos_b[t];
    if (t >= 16 && t < 24) sdimL[t-16] = 1.0f / powf(1000.0f, 0.125f*(float)(t-16));
    __syncthreads();

    {
        const int nl = t >> 7;
        const int m  = t & 127;
        const int n  = n0 + nl;
        float pm[4];
        {
            float cxn = geomL[n][0], cyn = geomL[n][1];
            float rwn = 1.0f/geomL[n][2], rhn = 1.0f/geomL[n][3];
            pm[0] = __logf(fmaxf(fabsf((cxn - geomL[m][0]) * rwn), 1e-3f)) * 100.0f;
            pm[1] = __logf(fmaxf(fabsf((cyn - geomL[m][1]) * rhn), 1e-3f)) * 100.0f;
            pm[2] = (geomL[n][4] - geomL[m][4]) * 100.0f;
            pm[3] = (geomL[n][5] - geomL[m][5]) * 100.0f;
        }
        char* base = (char*)featL;
        #pragma unroll
        for (int f = 0; f < 4; ++f) {
            float s[8], c[8];
            #pragma unroll
            for (int r = 0; r < 8; ++r) {
                __sincosf(pm[f] * sdimL[r], &s[r], &c[r]);
            }
            unsigned short us[8], uc[8];
            #pragma unroll
            for (int r = 0; r < 8; ++r) { us[r] = f2bf(s[r]); uc[r] = f2bf(c[r]); }
            *(uint4*)(base + ADDR128(t, 2*f)) =
                make_uint4((unsigned)us[0] | ((unsigned)us[1] << 16),
                           (unsigned)us[2] | ((unsigned)us[3] << 16),
                           (unsigned)us[4] | ((unsigned)us[5] << 16),
                           (unsigned)us[6] | ((unsigned)us[7] << 16));
            *(uint4*)(base + ADDR128(t, 2*f + 1)) =
                make_uint4((unsigned)uc[0] | ((unsigned)uc[1] << 16),
                           (unsigned)uc[2] | ((unsigned)uc[3] << 16),
                           (unsigned)uc[4] | ((unsigned)uc[5] << 16),
                           (unsigned)uc[6] | ((unsigned)uc[7] << 16));
        }
    }
    __syncthreads();

    {
        const int wave = t >> 6, lane = t & 63;
        const int lr = lane & 15, lh = lane >> 4;
        const float pbg = pbL[lr];           // g = lr
        #pragma unroll
        for (int ti = 0; ti < 4; ++ti) {
            const int t16 = wave*4 + ti;
            f32x4 acc = {0,0,0,0};
            #pragma unroll
            for (int ks = 0; ks < 2; ++ks) {
                bf16x8 a  = *(const bf16x8*)((char*)featL + ADDR128(t16*16 + lr, ks*4 + lh));
                bf16x8 bb = *(const bf16x8*)((char*)poswL + ADDR128(lr, ks*4 + lh));
                acc = __builtin_amdgcn_mfma_f32_16x16x32_bf16(a, bb, acc, 0, 0, 0);
            }
            const int g = lr;
            #pragma unroll
            for (int reg = 0; reg < 4; ++reg) {
                int p = t16*16 + lh*4 + reg;
                int n = n0 + (p >> 7);
                int m = p & 127;
                float w = fmaxf(fmaxf(acc[reg] + pbg, 0.0f), 1e-6f);
                lw[(((size_t)(b*C_ + cl)*FN_ + n)*G_ + g)*FN_ + m] = f2h(__logf(w));
            }
        }
    }
}

// ============ MFMA attention per (batch, class, group) — 70.5 KB LDS ============
// region FT (34816 B, rows stride 272B): ft bf16 -> aff f16 -> P bf16
#define FT_OFF   0
#define QL_OFF   34816    // q bf16 [128n][64dq] swz 16 KB
#define KL_OFF   51200    // k bf16 [128m][64dq] swz 16 KB
#define VT_OFF   67584    // V'^T bf16 [16e][128m] swz 4 KB
#define BIAS_OFF 71680    // 128 f32
#define SMEM_SZ  72192

__global__ __launch_bounds__(1024, 8) void k_attn(const unsigned short* __restrict__ embB,
                                               const unsigned short* __restrict__ wt,
                                               const float* __restrict__ q_b,
                                               const float* __restrict__ k_b,
                                               const float* __restrict__ out_b,
                                               const unsigned short* __restrict__ lw,
                                               float* __restrict__ att)
{
    // XCD-aligned decode: all 16 g-blocks of one bc share bid%8 (same XCD L2)
    const int bc   = blockIdx.x % (B_*C_);
    const int g    = blockIdx.x / (B_*C_);
    const int cl   = bc % C_;
    const int b    = bc / C_;
    const int c    = cl;
    const int t  = threadIdx.x;
    const int wave = t >> 6;
    const int lane = t & 63;
    const int lr = lane & 15;
    const int lh = lane >> 4;              // 0..3

    __shared__ char smem[SMEM_SZ];
    float* biasL = (float*)(smem + BIAS_OFF);

    // ---- prefetch lw row into registers (consumed in P3; hides L3/HBM latency)
    uint4 gl0, gl1;
    {
        const int row_p = t >> 3;
        const int lp_p  = t & 7;
        const unsigned short* lwrow = lw + (((size_t)bc*FN_ + row_p)*G_ + g)*FN_ + lp_p*16;
        gl0 = *(const uint4*)(lwrow);
        gl1 = *(const uint4*)(lwrow + 8);
    }

    // ================= P0: staging (ft copy bf16 + VT-zero + bias) =================
    {
        const char* src = (const char*)embB + ((size_t)(b*FN_)*C_ + c)*FC_*2;
        #pragma unroll
        for (int s = 0; s < 2; ++s) {
            int fi = t + s*1024;
            int n  = fi >> 4;
            int o16 = (fi & 15) * 16;
            uint4 v = *(const uint4*)(src + (size_t)n*C_*FC_*2 + o16);
            *(uint4*)(smem + FT_OFF + n*272 + o16) = v;
        }
    }
    if (t >= 512 && t < 768) {
        int i = t - 512;
        *(uint2*)(smem + VT_OFF + 8*256 + i*8) = make_uint2(0u, 0u);
    }
    if (t >= 128 && t < 256) {
        int r = t - 128;
        biasL[r] = (r < 64) ? q_b[g*DQ_ + r] : k_b[g*DQ_ + (r-64)];
    }
    __syncthreads();

    // ================= P1: proj MFMA (A from pre-transposed bf16 WT) =================
    {
        const int rb = (wave >> 2) * 32;
        const int nb = (wave & 3) * 32;
        const char* wtg = (const char*)wt + (size_t)g*144*256;
        f32x4 acc00 = {0,0,0,0}, acc01 = {0,0,0,0}, acc10 = {0,0,0,0}, acc11 = {0,0,0,0};
        f32x4 accV  = {0,0,0,0};
        #pragma unroll
        for (int ks = 0; ks < 4; ++ks) {
            const int fo = ks*64 + lh*16;
            bf16x8 a0 = *(const bf16x8*)(wtg + (rb + lr)*256 + fo);
            bf16x8 a1 = *(const bf16x8*)(wtg + (rb + 16 + lr)*256 + fo);
            bf16x8 b0 = *(const bf16x8*)(smem + FT_OFF + (nb + lr)*272 + fo);
            bf16x8 b1 = *(const bf16x8*)(smem + FT_OFF + (nb + 16 + lr)*272 + fo);
            acc00 = __builtin_amdgcn_mfma_f32_16x16x32_bf16(a0, b0, acc00, 0, 0, 0);
            acc01 = __builtin_amdgcn_mfma_f32_16x16x32_bf16(a0, b1, acc01, 0, 0, 0);
            acc10 = __builtin_amdgcn_mfma_f32_16x16x32_bf16(a1, b0, acc10, 0, 0, 0);
            acc11 = __builtin_amdgcn_mfma_f32_16x16x32_bf16(a1, b1, acc11, 0, 0, 0);
            if (wave < 8) {
                bf16x8 av = *(const bf16x8*)(wtg + (128 + lr)*256 + fo);
                bf16x8 bv = *(const bf16x8*)(smem + FT_OFF + (wave*16 + lr)*272 + fo);
                accV = __builtin_amdgcn_mfma_f32_16x16x32_bf16(av, bv, accV, 0, 0, 0);
            }
        }
        #pragma unroll
        for (int ti = 0; ti < 2; ++ti) {
            #pragma unroll
            for (int tj = 0; tj < 2; ++tj) {
                f32x4 a = (ti == 0) ? (tj == 0 ? acc00 : acc01) : (tj == 0 ? acc10 : acc11);
                int r0 = rb + ti*16 + lh*4;
                int n  = nb + tj*16 + lr;
                float v0 = a[0] + biasL[r0+0];
                float v1 = a[1] + biasL[r0+1];
                float v2 = a[2] + biasL[r0+2];
                float v3 = a[3] + biasL[r0+3];
                int dq0 = r0 & 63;
                int off = (r0 < 64 ? QL_OFF : KL_OFF);
                char* dst = smem + off + ADDR128(n, dq0 >> 3) + ((dq0 >> 2) & 1)*8;
                *(uint2*)dst = make_uint2((unsigned)f2bf(v0) | ((unsigned)f2bf(v1) << 16),
                                          (unsigned)f2bf(v2) | ((unsigned)f2bf(v3) << 16));
            }
        }
        if (wave < 8 && lh < 2) {
            int m = wave*16 + lr;
            #pragma unroll
            for (int reg = 0; reg < 4; ++reg) {
                int e = lh*4 + reg;
                char* dst = smem + VT_OFF + (e)*256 + ((((m >> 3) ^ e)) << 4) + (m & 7)*2;
                *(unsigned short*)dst = f2bf(accV[reg]);
            }
        }
    }
    __syncthreads();

    // ================= P2: aff MFMA -> f16 into FT region (ft is dead) =================
    {
        const int nb = (wave >> 2) * 32;
        const int mb = (wave & 3) * 32;
        f32x4 acc00 = {0,0,0,0}, acc01 = {0,0,0,0}, acc10 = {0,0,0,0}, acc11 = {0,0,0,0};
        #pragma unroll
        for (int ks = 0; ks < 2; ++ks) {
            int soff = ((ks*4 + lh) ^ (lr & 7)) << 4;
            bf16x8 a0 = *(const bf16x8*)(smem + QL_OFF + (nb + lr)*128 + soff);
            bf16x8 a1 = *(const bf16x8*)(smem + QL_OFF + (nb + 16 + lr)*128 + soff);
            bf16x8 b0 = *(const bf16x8*)(smem + KL_OFF + (mb + lr)*128 + soff);
            bf16x8 b1 = *(const bf16x8*)(smem + KL_OFF + (mb + 16 + lr)*128 + soff);
            acc00 = __builtin_amdgcn_mfma_f32_16x16x32_bf16(a0, b0, acc00, 0, 0, 0);
            acc01 = __builtin_amdgcn_mfma_f32_16x16x32_bf16(a0, b1, acc01, 0, 0, 0);
            acc10 = __builtin_amdgcn_mfma_f32_16x16x32_bf16(a1, b0, acc10, 0, 0, 0);
            acc11 = __builtin_amdgcn_mfma_f32_16x16x32_bf16(a1, b1, acc11, 0, 0, 0);
        }
        #pragma unroll
        for (int ti = 0; ti < 2; ++ti) {
            #pragma unroll
            for (int tj = 0; tj < 2; ++tj) {
                f32x4 a = (ti == 0) ? (tj == 0 ? acc00 : acc01) : (tj == 0 ? acc10 : acc11);
                int n0 = nb + ti*16 + lh*4;
                int m  = mb + tj*16 + lr;
                #pragma unroll
                for (int reg = 0; reg < 4; ++reg)
                    *(unsigned short*)(smem + FT_OFF + (n0 + reg)*272 + 2*m) = f2h(a[reg]);
            }
        }
    }
    __syncthreads();

    // ================= P3: softmax (aff f16 LDS + prefetched lw regs) -> P bf16 in place =================
    {
        const int row = t >> 3;
        const int lp  = t & 7;
        char* abase = smem + FT_OFF + row*272 + lp*32;
        uint4 af0 = *(const uint4*)abase;
        uint4 af1 = *(const uint4*)(abase + 16);
        const unsigned short* ah0 = (const unsigned short*)&af0;
        const unsigned short* ah1 = (const unsigned short*)&af1;
        const unsigned short* lp0 = (const unsigned short*)&gl0;
        const unsigned short* lp1 = (const unsigned short*)&gl1;
        float v[16];
        float mx = -INFINITY;
        #pragma unroll
        for (int j = 0; j < 8; ++j) {
            float val = h2f(ah0[j])*0.125f + h2f(lp0[j]);
            v[j] = val; mx = fmaxf(mx, val);
        }
        #pragma unroll
        for (int j = 0; j < 8; ++j) {
            float val = h2f(ah1[j])*0.125f + h2f(lp1[j]);
            v[8+j] = val; mx = fmaxf(mx, val);
        }
        #pragma unroll
        for (int s = 1; s < 8; s <<= 1) mx = fmaxf(mx, __shfl_xor(mx, s, 8));
        float sum = 0.f;
        #pragma unroll
        for (int j = 0; j < 16; ++j) { v[j] = __expf(v[j] - mx); sum += v[j]; }
        #pragma unroll
        for (int s = 1; s < 8; s <<= 1) sum += __shfl_xor(sum, s, 8);
        float rs = 1.0f / sum;
        unsigned short u[16];
        #pragma unroll
        for (int j = 0; j < 16; ++j) u[j] = f2bf(v[j] * rs);
        *(uint4*)abase = make_uint4((unsigned)u[0] | ((unsigned)u[1] << 16),
                                    (unsigned)u[2] | ((unsigned)u[3] << 16),
                                    (unsigned)u[4] | ((unsigned)u[5] << 16),
                                    (unsigned)u[6] | ((unsigned)u[7] << 16));
        *(uint4*)(abase + 16) = make_uint4((unsigned)u[8]  | ((unsigned)u[9]  << 16),
                                           (unsigned)u[10] | ((unsigned)u[11] << 16),
                                           (unsigned)u[12] | ((unsigned)u[13] << 16),
                                           (unsigned)u[14] | ((unsigned)u[15] << 16));
    }
    __syncthreads();

    // ================= P4: att = P @ V' =================
    if (wave < 8) {
        const int tb = wave * 16;
        f32x4 acc = {0,0,0,0};
        #pragma unroll
        for (int ks = 0; ks < 4; ++ks) {
            const int fo = ks*64 + lh*16;
            int soff = ((ks*4 + lh) ^ lr) << 4;
            bf16x8 a = *(const bf16x8*)(smem + FT_OFF + (tb + lr)*272 + fo);
            bf16x8 bv = *(const bf16x8*)(smem + VT_OFF + lr*256 + soff);
            acc = __builtin_amdgcn_mfma_f32_16x16x32_bf16(a, bv, acc, 0, 0, 0);
        }
        if (lr < 8) {
            float ob = out_b[g*EO_ + lr];
            #pragma unroll
            for (int reg = 0; reg < 4; ++reg) {
                int n = tb + lh*4 + reg;
                att[((size_t)(b*FN_ + n)*C_ + c)*FC_ + g*EO_ + lr] = acc[reg] + ob;
            }
        }
    }
}

// ============ final: 8 items/block, 32 lanes/item ============
__global__ __launch_bounds__(256) void k_final(const float* __restrict__ emb_feat,
                                               const float* __restrict__ att,
                                               const float* __restrict__ logit_w,
                                               const float* __restrict__ logit_b,
                                               const float* __restrict__ sorted_score,
                                               float* __restrict__ out)
{
    __shared__ float lwL[FC_*NT_ + NT_];
    const int t = threadIdx.x;
    for (int i = t; i < FC_*NT_ + NT_; i += 256)
        lwL[i] = (i < FC_*NT_) ? logit_w[i] : logit_b[i - FC_*NT_];
    __syncthreads();
    const int item = blockIdx.x*8 + (t >> 5);
    const int l = t & 31;
    const int d0 = l*4;
    float4 ev = *(const float4*)(emb_feat + (size_t)item*FC_ + d0);
    float4 av = *(const float4*)(att + (size_t)item*FC_ + d0);
    float a0 = fmaxf(ev.x + av.x, 0.f);
    float a1 = fmaxf(ev.y + av.y, 0.f);
    float a2 = fmaxf(ev.z + av.z, 0.f);
    float a3 = fmaxf(ev.w + av.w, 0.f);
    float s0 = a0*lwL[(d0+0)*NT_+0] + a1*lwL[(d0+1)*NT_+0] + a2*lwL[(d0+2)*NT_+0] + a3*lwL[(d0+3)*NT_+0];
    float s1 = a0*lwL[(d0+0)*NT_+1] + a1*lwL[(d0+1)*NT_+1] + a2*lwL[(d0+2)*NT_+1] + a3*lwL[(d0+3)*NT_+1];
    float s2 = a0*lwL[(d0+0)*NT_+2] + a1*lwL[(d0+1)*NT_+2] + a2*lwL[(d0+2)*NT_+2] + a3*lwL[(d0+3)*NT_+2];
    #pragma unroll
    for (int s = 1; s < 32; s <<= 1) {
        s0 += __shfl_xor(s0, s, 32);
        s1 += __shfl_xor(s1, s, 32);
        s2 += __shfl_xor(s2, s, 32);
    }
    if (l < NT_) {
        float lg = (l == 0) ? s0 : (l == 1) ? s1 : s2;
        lg += lwL[FC_*NT_ + l];
        float sg = 1.f / (1.f + expf(-lg));
        out[(size_t)item*NT_ + l] = sg * sorted_score[item];
    }
}

extern "C" void kernel_launch(void* const* d_in, const int* in_sizes, int n_in,
                              void* d_out, int out_size, void* d_ws, size_t ws_size,
                              hipStream_t stream) {
    (void)in_sizes; (void)n_in; (void)out_size; (void)ws_size;
    const float* roi_feat = (const float*)d_in[0];
    const float* scores   = (const float*)d_in[1];
    const float* pdeltas  = (const float*)d_in[2];
    const float* pboxes   = (const float*)d_in[3];
    const float* roi_w    = (const float*)d_in[4];
    const float* roi_b    = (const float*)d_in[5];
    const float* rank_w   = (const float*)d_in[6];
    const float* rank_b   = (const float*)d_in[7];
    const float* logit_w  = (const float*)d_in[8];
    const float* logit_b  = (const float*)d_in[9];
    const float* pos_w    = (const float*)d_in[10];
    const float* pos_b    = (const float*)d_in[11];
    const float* q_w      = (const float*)d_in[12];
    const float* q_b      = (const float*)d_in[13];
    const float* k_w      = (const float*)d_in[14];
    const float* k_b      = (const float*)d_in[15];
    const float* out_w    = (const float*)d_in[16];
    const float* out_b    = (const float*)d_in[17];
    float* ws = (float*)d_ws;

    float* roiP         = ws + O_ROIP;
    float* rankP        = ws + O_RANKP;
    int*   rank_idx     = (int*)(ws + O_RANKIDX);
    float* sorted_score = ws + O_SSCORE;
    float* sorted_boxes = ws + O_SBOX;
    float* emb_feat     = ws + O_EMB;
    float* att          = ws + O_ATT;
    unsigned short* lwb = (unsigned short*)(ws + O_LW);
    unsigned short* wtb = (unsigned short*)(ws + O_WT);
    unsigned short* embB = (unsigned short*)(ws + O_EMBB);

    k_embed<<<dim3(160), dim3(256), 0, stream>>>(roi_feat, roi_w, roi_b, rank_w, rank_b,
                                                 q_w, k_w, out_w, roiP, rankP, wtb);
    k_topk<<<dim3(B_*C_), dim3(512), 0, stream>>>(scores, rank_idx, sorted_score);
    k_gather<<<dim3(B_*FN_*C_/8), dim3(256), 0, stream>>>(rank_idx, roiP, rankP,
                                                          pdeltas, pboxes, emb_feat, embB, sorted_boxes);
    k_pos2<<<dim3(B_*C_*64), dim3(256), 0, stream>>>(sorted_boxes, pos_w, pos_b, lwb);
    k_attn<<<dim3(B_*C_*G_), dim3(1024), 0, stream>>>(embB, wtb, q_b, k_b, out_b, lwb, att);
    k_final<<<dim3(B_*FN_*C_/8), dim3(256), 0, stream>>>(emb_feat, att, logit_w, logit_b,
                                                         sorted_score, d_out ? (float*)d_out : nullptr);
}

// Round 12
// 185.980 us; speedup vs baseline: 1.0525x; 1.0469x over previous
//
#include <hip/hip_runtime.h>
#include <math.h>

#define B_    2
#define NB_   512
#define C_    80
#define FEAT_ 1024
#define FN_   128
#define FC_   128
#define PE_   64
#define G_    16
#define DQ_   64
#define EO_   8
#define NT_   3
#define SCALE_CLAMP_ 4.135166556742356f

typedef __attribute__((ext_vector_type(8))) short bf16x8;
typedef __attribute__((ext_vector_type(4))) float f32x4;

// ---- workspace layout (float offsets) ----
#define O_ROIP    ((size_t)0)                                   // 4*1024*128 (K-quarter partials)
#define O_RANKP   (O_ROIP + (size_t)4*B_*NB_*FC_)               // 4*128*128
#define O_RANKIDX (O_RANKP + (size_t)4*FN_*FC_)                 // B*128*80 (int)
#define O_SSCORE  (O_RANKIDX + (size_t)B_*FN_*C_)               // B*128*80
#define O_SBOX    (O_SSCORE + (size_t)B_*FN_*C_)                // B*128*80*4
#define O_EMB     (O_SBOX + (size_t)B_*FN_*C_*4)                // B*128*80*128
#define O_ATT     (O_EMB + (size_t)B_*FN_*C_*FC_)               // B*128*80*128
#define O_LW      (O_ATT + (size_t)B_*FN_*C_*FC_)               // 2*80*128*16*128 f16 = 84MB (log w)
#define O_WT      (O_LW + (size_t)B_*C_*FN_*G_*FN_/2)           // 16*144*128 bf16
#define O_EMBB    (O_WT + (size_t)16*144*128/2)                 // B*128*80*128 bf16

__device__ __forceinline__ float bf2f(unsigned short u) {
    return __uint_as_float(((unsigned int)u) << 16);
}
__device__ __forceinline__ unsigned short f2bf(float f) {
    unsigned int x = __float_as_uint(f);
    unsigned int r = (x + 0x7fff + ((x >> 16) & 1)) >> 16;   // RNE
    return (unsigned short)r;
}
__device__ __forceinline__ unsigned short f2h(float x) {
    _Float16 h = (_Float16)x;
    return __builtin_bit_cast(unsigned short, h);
}
__device__ __forceinline__ float h2f(unsigned short u) {
    _Float16 h = __builtin_bit_cast(_Float16, u);
    return (float)h;
}

// 16B-granule swizzle, 128B row (8 granules)
#define ADDR128(row, gr)  ((row)*128 + ((((gr) ^ ((row)&7))) << 4))

// ============ embed GEMMs (blocks 0..287: 72 row-tiles x 4 K-quarters) + WT prep (288..303) ============
__global__ __launch_bounds__(256) void k_embed(const float* __restrict__ roi_feat,
                                               const float* __restrict__ roi_w,
                                               const float* __restrict__ roi_b,
                                               const float* __restrict__ rank_w,
                                               const float* __restrict__ rank_b,
                                               const float* __restrict__ q_w,
                                               const float* __restrict__ k_w,
                                               const float* __restrict__ out_w,
                                               float* __restrict__ roiP,
                                               float* __restrict__ rankP,
                                               unsigned short* __restrict__ wtg)
{
    const int bid = blockIdx.x;
    const int t = threadIdx.x;
    if (bid >= 288) {
        // ---- WT prep: WT[g][144][128] bf16 (Wq^T | Wk^T | Wo^T | zeros)
        const int g = bid - 288;
        for (int idx = t; idx < 144*16; idx += 256) {
            const int row = idx >> 4;
            const int kc  = (idx & 15) * 8;
            unsigned short u[8];
            if (row < 64) {
                #pragma unroll
                for (int j = 0; j < 8; ++j) u[j] = f2bf(q_w[(size_t)(kc + j)*1024 + g*DQ_ + row]);
            } else if (row < 128) {
                const int r = row - 64;
                #pragma unroll
                for (int j = 0; j < 8; ++j) u[j] = f2bf(k_w[(size_t)(kc + j)*1024 + g*DQ_ + r]);
            } else if (row < 136) {
                const int e = row - 128;
                #pragma unroll
                for (int j = 0; j < 8; ++j) u[j] = f2bf(out_w[(size_t)g*FC_*EO_ + (size_t)(kc + j)*EO_ + e]);
            } else {
                #pragma unroll
                for (int j = 0; j < 8; ++j) u[j] = 0;
            }
            *(uint4*)(wtg + (size_t)g*144*128 + row*128 + kc) =
                make_uint4((unsigned)u[0] | ((unsigned)u[1] << 16),
                           (unsigned)u[2] | ((unsigned)u[3] << 16),
                           (unsigned)u[4] | ((unsigned)u[5] << 16),
                           (unsigned)u[6] | ((unsigned)u[7] << 16));
        }
        return;
    }
    const int kq  = bid & 3;
    const int rt  = bid >> 2;            // 0..71
    const bool isRank = rt >= 64;
    const int row0 = (isRank ? rt - 64 : rt) * 16;
    const int w = t >> 6, lane = t & 63, lr = lane & 15, lh = lane >> 4;
    const int col0 = w * 32;
    const float* W = isRank ? rank_w : roi_w;
    const float* bias = isRank ? rank_b : roi_b;

    const int arow = row0 + lr;
    f32x4 acc0 = {0,0,0,0}, acc1 = {0,0,0,0};

    #pragma unroll 4
    for (int ks = 0; ks < 8; ++ks) {
        const int kb = kq*256 + ks*32 + lh*8;
        bf16x8 af;
        if (!isRank) {
            float4 a0 = *(const float4*)(roi_feat + (size_t)arow*FEAT_ + kb);
            float4 a1 = *(const float4*)(roi_feat + (size_t)arow*FEAT_ + kb + 4);
            af[0] = (short)f2bf(a0.x); af[1] = (short)f2bf(a0.y);
            af[2] = (short)f2bf(a0.z); af[3] = (short)f2bf(a0.w);
            af[4] = (short)f2bf(a1.x); af[5] = (short)f2bf(a1.y);
            af[6] = (short)f2bf(a1.z); af[7] = (short)f2bf(a1.w);
        } else {
            #pragma unroll
            for (int j = 0; j < 8; ++j) {
                int k = kb + j;
                int kk = k & 511;
                float inv = exp2f(-(float)kk * 0.0194644226f);  // log2(1000)/512
                float arg = (float)arow * inv;
                float v = (k < 512) ? __sinf(arg) : __cosf(arg);
                af[j] = (short)f2bf(v);
            }
        }
        bf16x8 bf0, bf1;
        #pragma unroll
        for (int j = 0; j < 8; ++j) {
            const float* wr = W + (size_t)(kb + j)*FC_ + col0 + lr;
            bf0[j] = (short)f2bf(wr[0]);
            bf1[j] = (short)f2bf(wr[16]);
        }
        acc0 = __builtin_amdgcn_mfma_f32_16x16x32_bf16(af, bf0, acc0, 0, 0, 0);
        acc1 = __builtin_amdgcn_mfma_f32_16x16x32_bf16(af, bf1, acc1, 0, 0, 0);
    }
    float* dst = isRank ? (rankP + (size_t)kq*FN_*FC_) : (roiP + (size_t)kq*(B_*NB_)*FC_);
    #pragma unroll
    for (int tile = 0; tile < 2; ++tile) {
        f32x4 a = tile ? acc1 : acc0;
        int col = col0 + tile*16 + lr;
        float bv = (kq == 0) ? bias[col] : 0.0f;
        #pragma unroll
        for (int reg = 0; reg < 4; ++reg) {
            int rr = row0 + lh*4 + reg;
            dst[(size_t)rr*FC_ + col] = a[reg] + bv;
        }
    }
}

// ============ softmax over boxes + stable top-128 rank ============
__global__ __launch_bounds__(512) void k_topk(const float* __restrict__ scores,
                                              int* __restrict__ rank_idx,
                                              float* __restrict__ sorted_score)
{
    int b = blockIdx.x / C_, c = blockIdx.x % C_;
    __shared__ float p[NB_];
    __shared__ float red[NB_];
    int i = threadIdx.x;
    float s = scores[(size_t)(b*NB_ + i)*(C_+1) + c];
    red[i] = s; __syncthreads();
    for (int o = 256; o > 0; o >>= 1) { if (i < o) red[i] = fmaxf(red[i], red[i+o]); __syncthreads(); }
    float mx = red[0]; __syncthreads();
    float e = expf(s - mx);
    red[i] = e; __syncthreads();
    for (int o = 256; o > 0; o >>= 1) { if (i < o) red[i] += red[i+o]; __syncthreads(); }
    float sum = red[0]; __syncthreads();
    float pi = e / sum;
    p[i] = pi; __syncthreads();
    int rank = 0;
    for (int j4 = 0; j4 < NB_/4; ++j4) {
        float4 pj = *(const float4*)&p[j4*4];
        int j = j4*4;
        rank += (pj.x > pi) || (pj.x == pi && (j+0) < i);
        rank += (pj.y > pi) || (pj.y == pi && (j+1) < i);
        rank += (pj.z > pi) || (pj.z == pi && (j+2) < i);
        rank += (pj.w > pi) || (pj.w == pi && (j+3) < i);
    }
    if (rank < FN_) {
        rank_idx[(size_t)(b*FN_ + rank)*C_ + c] = i;
        sorted_score[(size_t)(b*FN_ + rank)*C_ + c] = pi;
    }
}

// ============ gather emb_feat (sum 4 K-quarter partials, +bf16 copy) + refined boxes ============
__global__ __launch_bounds__(256) void k_gather(const int* __restrict__ rank_idx,
                                                const float* __restrict__ roiP,
                                                const float* __restrict__ rankP,
                                                const float* __restrict__ pdeltas,
                                                const float* __restrict__ pboxes,
                                                float* __restrict__ emb_feat,
                                                unsigned short* __restrict__ embB,
                                                float* __restrict__ sorted_boxes)
{
    const int t = threadIdx.x;
    const int item = blockIdx.x*8 + (t >> 5);
    const int l = t & 31;
    const int c = item % C_;
    const int bn = item / C_;
    const int n = bn & (FN_-1);
    const int b = bn >> 7;
    const int idx = rank_idx[item];
    const int row = b*NB_ + idx;
    float4 sm = make_float4(0.f, 0.f, 0.f, 0.f);
    #pragma unroll
    for (int kq = 0; kq < 4; ++kq) {
        float4 e = *(const float4*)(roiP + (size_t)(kq*B_*NB_ + row)*FC_ + l*4);
        float4 r = *(const float4*)(rankP + (size_t)(kq*FN_ + n)*FC_ + l*4);
        sm.x += e.x + r.x; sm.y += e.y + r.y; sm.z += e.z + r.z; sm.w += e.w + r.w;
    }
    *(float4*)(emb_feat + (size_t)item*FC_ + l*4) = sm;
    *(uint2*)(embB + (size_t)item*FC_ + l*4) =
        make_uint2((unsigned)f2bf(sm.x) | ((unsigned)f2bf(sm.y) << 16),
                   (unsigned)f2bf(sm.z) | ((unsigned)f2bf(sm.w) << 16));
    if (l == 0) {
        float x1 = pboxes[row*4+0], y1 = pboxes[row*4+1], x2 = pboxes[row*4+2], y2 = pboxes[row*4+3];
        float w = x2 - x1, h = y2 - y1;
        float cx = x1 + 0.5f*w, cy = y1 + 0.5f*h;
        const float* dl = pdeltas + (size_t)row*(C_*4) + c*4;
        float dx = dl[0]/10.0f, dy = dl[1]/10.0f;
        float dw = fminf(dl[2]/5.0f, SCALE_CLAMP_);
        float dh = fminf(dl[3]/5.0f, SCALE_CLAMP_);
        float pcx = dx*w + cx, pcy = dy*h + cy;
        float pw = expf(dw)*w, ph = expf(dh)*h;
        float* ob = sorted_boxes + (size_t)item*4;
        ob[0] = pcx - 0.5f*pw; ob[1] = pcy - 0.5f*ph;
        ob[2] = pcx + 0.5f*pw; ob[3] = pcy + 0.5f*ph;
    }
}

// ============ prior via MFMA -> store f16(log w) ============
__global__ __launch_bounds__(256) void k_pos2(const float* __restrict__ sorted_boxes,
                                              const float* __restrict__ pos_w,
                                              const float* __restrict__ pos_b,
                                              unsigned short* __restrict__ lw)
{
    const int n2   = blockIdx.x & 63;
    const int rest = blockIdx.x >> 6;
    const int cl   = rest % C_;
    const int b    = rest / C_;
    const int n0   = n2 * 2;
    const int t    = threadIdx.x;

    __shared__ float geomL[FN_][6];               // 3 KB
    __shared__ unsigned short featL[256*PE_];     // 32 KB, swizzled 128B rows
    __shared__ unsigned short poswL[G_*PE_];      // 2 KB, swizzled 128B rows
    __shared__ float pbL[G_];
    __shared__ float sdimL[8];

    if (t < FN_) {
        const float* bx = sorted_boxes + (((size_t)(b*FN_ + t))*C_ + cl)*4;
        float x1 = bx[0], y1 = bx[1], x2 = bx[2], y2 = bx[3];
        float w = x2 - x1 + 1.0f;
        float h = y2 - y1 + 1.0f;
        geomL[t][0] = 0.5f*(x1+x2);
        geomL[t][1] = 0.5f*(y1+y2);
        geomL[t][2] = w;
        geomL[t][3] = h;
        geomL[t][4] = __logf(w);
        geomL[t][5] = __logf(h);
    } else {
        int id = t - 128;
        int g  = id >> 3;
        int gr = id & 7;
        unsigned short u[8];
        #pragma unroll
        for (int j = 0; j < 8; ++j) u[j] = f2bf(pos_w[(gr*8 + j)*G_ + g]);
        *(uint4*)((char*)poswL + ADDR128(g, gr)) =
            make_uint4((unsigned)u[0] | ((unsigned)u[1] << 16),
                       (unsigned)u[2] | ((unsigned)u[3] << 16),
                       (unsigned)u[4] | ((unsigned)u[5] << 16),
                       (unsigned)u[6] | ((unsigned)u[7] << 16));
    }
    if (t < G_) pbL[t] = pos_b[t];
    if (t >= 16 && t < 24) sdimL[t-16] = 1.0f / powf(1000.0f, 0.125f*(float)(t-16));
    __syncthreads();

    {
        const int nl = t >> 7;
        const int m  = t & 127;
        const int n  = n0 + nl;
        float pm[4];
        {
            float cxn = geomL[n][0], cyn = geomL[n][1];
            float rwn = 1.0f/geomL[n][2], rhn = 1.0f/geomL[n][3];
            pm[0] = __logf(fmaxf(fabsf((cxn - geomL[m][0]) * rwn), 1e-3f)) * 100.0f;
            pm[1] = __logf(fmaxf(fabsf((cyn - geomL[m][1]) * rhn), 1e-3f)) * 100.0f;
            pm[2] = (geomL[n][4] - geomL[m][4]) * 100.0f;
            pm[3] = (geomL[n][5] - geomL[m][5]) * 100.0f;
        }
        char* base = (char*)featL;
        #pragma unroll
        for (int f = 0; f < 4; ++f) {
            float s[8], c[8];
            #pragma unroll
            for (int r = 0; r < 8; ++r) {
                __sincosf(pm[f] * sdimL[r], &s[r], &c[r]);
            }
            unsigned short us[8], uc[8];
            #pragma unroll
            for (int r = 0; r < 8; ++r) { us[r] = f2bf(s[r]); uc[r] = f2bf(c[r]); }
            *(uint4*)(base + ADDR128(t, 2*f)) =
                make_uint4((unsigned)us[0] | ((unsigned)us[1] << 16),
                           (unsigned)us[2] | ((unsigned)us[3] << 16),
                           (unsigned)us[4] | ((unsigned)us[5] << 16),
                           (unsigned)us[6] | ((unsigned)us[7] << 16));
            *(uint4*)(base + ADDR128(t, 2*f + 1)) =
                make_uint4((unsigned)uc[0] | ((unsigned)uc[1] << 16),
                           (unsigned)uc[2] | ((unsigned)uc[3] << 16),
                           (unsigned)uc[4] | ((unsigned)uc[5] << 16),
                           (unsigned)uc[6] | ((unsigned)uc[7] << 16));
        }
    }
    __syncthreads();

    {
        const int wave = t >> 6, lane = t & 63;
        const int lr = lane & 15, lh = lane >> 4;
        const float pbg = pbL[lr];           // g = lr
        #pragma unroll
        for (int ti = 0; ti < 4; ++ti) {
            const int t16 = wave*4 + ti;
            f32x4 acc = {0,0,0,0};
            #pragma unroll
            for (int ks = 0; ks < 2; ++ks) {
                bf16x8 a  = *(const bf16x8*)((char*)featL + ADDR128(t16*16 + lr, ks*4 + lh));
                bf16x8 bb = *(const bf16x8*)((char*)poswL + ADDR128(lr, ks*4 + lh));
                acc = __builtin_amdgcn_mfma_f32_16x16x32_bf16(a, bb, acc, 0, 0, 0);
            }
            const int g = lr;
            #pragma unroll
            for (int reg = 0; reg < 4; ++reg) {
                int p = t16*16 + lh*4 + reg;
                int n = n0 + (p >> 7);
                int m = p & 127;
                float w = fmaxf(fmaxf(acc[reg] + pbg, 0.0f), 1e-6f);
                lw[(((size_t)(b*C_ + cl)*FN_ + n)*G_ + g)*FN_ + m] = f2h(__logf(w));
            }
        }
    }
}

// ============ MFMA attention per (batch, class, group) — 70.5 KB LDS ============
// region FT (34816 B, rows stride 272B): ft bf16 -> aff f16 -> P bf16
#define FT_OFF   0
#define QL_OFF   34816    // q bf16 [128n][64dq] swz 16 KB
#define KL_OFF   51200    // k bf16 [128m][64dq] swz 16 KB
#define VT_OFF   67584    // V'^T bf16 [16e][128m] swz 4 KB
#define BIAS_OFF 71680    // 128 f32
#define SMEM_SZ  72192

__global__ __launch_bounds__(1024, 8) void k_attn(const unsigned short* __restrict__ embB,
                                               const unsigned short* __restrict__ wt,
                                               const float* __restrict__ q_b,
                                               const float* __restrict__ k_b,
                                               const float* __restrict__ out_b,
                                               const unsigned short* __restrict__ lw,
                                               float* __restrict__ att)
{
    const int g    = blockIdx.x & 15;
    const int rest = blockIdx.x >> 4;
    const int cl   = rest % C_;
    const int b    = rest / C_;
    const int c    = cl;
    const int t  = threadIdx.x;
    const int wave = t >> 6;
    const int lane = t & 63;
    const int lr = lane & 15;
    const int lh = lane >> 4;              // 0..3

    __shared__ char smem[SMEM_SZ];
    float* biasL = (float*)(smem + BIAS_OFF);

    // ================= P0: staging (ft copy bf16 + VT-zero + bias) =================
    {
        const char* src = (const char*)embB + ((size_t)(b*FN_)*C_ + c)*FC_*2;
        #pragma unroll
        for (int s = 0; s < 2; ++s) {
            int fi = t + s*1024;
            int n  = fi >> 4;
            int o16 = (fi & 15) * 16;
            uint4 v = *(const uint4*)(src + (size_t)n*C_*FC_*2 + o16);
            *(uint4*)(smem + FT_OFF + n*272 + o16) = v;
        }
    }
    if (t >= 512 && t < 768) {
        int i = t - 512;
        *(uint2*)(smem + VT_OFF + 8*256 + i*8) = make_uint2(0u, 0u);
    }
    if (t >= 128 && t < 256) {
        int r = t - 128;
        biasL[r] = (r < 64) ? q_b[g*DQ_ + r] : k_b[g*DQ_ + (r-64)];
    }
    __syncthreads();

    // ================= P1: proj MFMA (A from pre-transposed bf16 WT) =================
    {
        const int rb = (wave >> 2) * 32;
        const int nb = (wave & 3) * 32;
        const char* wtg = (const char*)wt + (size_t)g*144*256;
        f32x4 acc00 = {0,0,0,0}, acc01 = {0,0,0,0}, acc10 = {0,0,0,0}, acc11 = {0,0,0,0};
        f32x4 accV  = {0,0,0,0};
        #pragma unroll
        for (int ks = 0; ks < 4; ++ks) {
            const int fo = ks*64 + lh*16;
            bf16x8 a0 = *(const bf16x8*)(wtg + (rb + lr)*256 + fo);
            bf16x8 a1 = *(const bf16x8*)(wtg + (rb + 16 + lr)*256 + fo);
            bf16x8 b0 = *(const bf16x8*)(smem + FT_OFF + (nb + lr)*272 + fo);
            bf16x8 b1 = *(const bf16x8*)(smem + FT_OFF + (nb + 16 + lr)*272 + fo);
            acc00 = __builtin_amdgcn_mfma_f32_16x16x32_bf16(a0, b0, acc00, 0, 0, 0);
            acc01 = __builtin_amdgcn_mfma_f32_16x16x32_bf16(a0, b1, acc01, 0, 0, 0);
            acc10 = __builtin_amdgcn_mfma_f32_16x16x32_bf16(a1, b0, acc10, 0, 0, 0);
            acc11 = __builtin_amdgcn_mfma_f32_16x16x32_bf16(a1, b1, acc11, 0, 0, 0);
            if (wave < 8) {
                bf16x8 av = *(const bf16x8*)(wtg + (128 + lr)*256 + fo);
                bf16x8 bv = *(const bf16x8*)(smem + FT_OFF + (wave*16 + lr)*272 + fo);
                accV = __builtin_amdgcn_mfma_f32_16x16x32_bf16(av, bv, accV, 0, 0, 0);
            }
        }
        #pragma unroll
        for (int ti = 0; ti < 2; ++ti) {
            #pragma unroll
            for (int tj = 0; tj < 2; ++tj) {
                f32x4 a = (ti == 0) ? (tj == 0 ? acc00 : acc01) : (tj == 0 ? acc10 : acc11);
                int r0 = rb + ti*16 + lh*4;
                int n  = nb + tj*16 + lr;
                float v0 = a[0] + biasL[r0+0];
                float v1 = a[1] + biasL[r0+1];
                float v2 = a[2] + biasL[r0+2];
                float v3 = a[3] + biasL[r0+3];
                int dq0 = r0 & 63;
                int off = (r0 < 64 ? QL_OFF : KL_OFF);
                char* dst = smem + off + ADDR128(n, dq0 >> 3) + ((dq0 >> 2) & 1)*8;
                *(uint2*)dst = make_uint2((unsigned)f2bf(v0) | ((unsigned)f2bf(v1) << 16),
                                          (unsigned)f2bf(v2) | ((unsigned)f2bf(v3) << 16));
            }
        }
        if (wave < 8 && lh < 2) {
            int m = wave*16 + lr;
            #pragma unroll
            for (int reg = 0; reg < 4; ++reg) {
                int e = lh*4 + reg;
                char* dst = smem + VT_OFF + (e)*256 + ((((m >> 3) ^ e)) << 4) + (m & 7)*2;
                *(unsigned short*)dst = f2bf(accV[reg]);
            }
        }
    }
    __syncthreads();

    // ================= P2: aff MFMA -> f16 into FT region (ft is dead) =================
    {
        const int nb = (wave >> 2) * 32;
        const int mb = (wave & 3) * 32;
        f32x4 acc00 = {0,0,0,0}, acc01 = {0,0,0,0}, acc10 = {0,0,0,0}, acc11 = {0,0,0,0};
        #pragma unroll
        for (int ks = 0; ks < 2; ++ks) {
            int soff = ((ks*4 + lh) ^ (lr & 7)) << 4;
            bf16x8 a0 = *(const bf16x8*)(smem + QL_OFF + (nb + lr)*128 + soff);
            bf16x8 a1 = *(const bf16x8*)(smem + QL_OFF + (nb + 16 + lr)*128 + soff);
            bf16x8 b0 = *(const bf16x8*)(smem + KL_OFF + (mb + lr)*128 + soff);
            bf16x8 b1 = *(const bf16x8*)(smem + KL_OFF + (mb + 16 + lr)*128 + soff);
            acc00 = __builtin_amdgcn_mfma_f32_16x16x32_bf16(a0, b0, acc00, 0, 0, 0);
            acc01 = __builtin_amdgcn_mfma_f32_16x16x32_bf16(a0, b1, acc01, 0, 0, 0);
            acc10 = __builtin_amdgcn_mfma_f32_16x16x32_bf16(a1, b0, acc10, 0, 0, 0);
            acc11 = __builtin_amdgcn_mfma_f32_16x16x32_bf16(a1, b1, acc11, 0, 0, 0);
        }
        #pragma unroll
        for (int ti = 0; ti < 2; ++ti) {
            #pragma unroll
            for (int tj = 0; tj < 2; ++tj) {
                f32x4 a = (ti == 0) ? (tj == 0 ? acc00 : acc01) : (tj == 0 ? acc10 : acc11);
                int n0 = nb + ti*16 + lh*4;
                int m  = mb + tj*16 + lr;
                #pragma unroll
                for (int reg = 0; reg < 4; ++reg)
                    *(unsigned short*)(smem + FT_OFF + (n0 + reg)*272 + 2*m) = f2h(a[reg]);
            }
        }
    }
    __syncthreads();

    // ================= P3: softmax (aff f16 + lw f16, vectorized) -> P bf16 in place =================
    {
        const int row = t >> 3;
        const int lp  = t & 7;
        const int m0  = lp * 16;
        const unsigned short* lwrow = lw + ((((size_t)(b*C_ + cl))*FN_ + row)*G_ + g)*FN_ + m0;
        uint4 gl0 = *(const uint4*)(lwrow);
        uint4 gl1 = *(const uint4*)(lwrow + 8);
        char* abase = smem + FT_OFF + row*272 + lp*32;
        uint4 af0 = *(const uint4*)abase;
        uint4 af1 = *(const uint4*)(abase + 16);
        const unsigned short* ah0 = (const unsigned short*)&af0;
        const unsigned short* ah1 = (const unsigned short*)&af1;
        const unsigned short* lp0 = (const unsigned short*)&gl0;
        const unsigned short* lp1 = (const unsigned short*)&gl1;
        float v[16];
        float mx = -INFINITY;
        #pragma unroll
        for (int j = 0; j < 8; ++j) {
            float val = h2f(ah0[j])*0.125f + h2f(lp0[j]);
            v[j] = val; mx = fmaxf(mx, val);
        }
        #pragma unroll
        for (int j = 0; j < 8; ++j) {
            float val = h2f(ah1[j])*0.125f + h2f(lp1[j]);
            v[8+j] = val; mx = fmaxf(mx, val);
        }
        #pragma unroll
        for (int s = 1; s < 8; s <<= 1) mx = fmaxf(mx, __shfl_xor(mx, s, 8));
        float sum = 0.f;
        #pragma unroll
        for (int j = 0; j < 16; ++j) { v[j] = __expf(v[j] - mx); sum += v[j]; }
        #pragma unroll
        for (int s = 1; s < 8; s <<= 1) sum += __shfl_xor(sum, s, 8);
        float rs = 1.0f / sum;
        unsigned short u[16];
        #pragma unroll
        for (int j = 0; j < 16; ++j) u[j] = f2bf(v[j] * rs);
        *(uint4*)abase = make_uint4((unsigned)u[0] | ((unsigned)u[1] << 16),
                                    (unsigned)u[2] | ((unsigned)u[3] << 16),
                                    (unsigned)u[4] | ((unsigned)u[5] << 16),
                                    (unsigned)u[6] | ((unsigned)u[7] << 16));
        *(uint4*)(abase + 16) = make_uint4((unsigned)u[8]  | ((unsigned)u[9]  << 16),
                                           (unsigned)u[10] | ((unsigned)u[11] << 16),
                                           (unsigned)u[12] | ((unsigned)u[13] << 16),
                                           (unsigned)u[14] | ((unsigned)u[15] << 16));
    }
    __syncthreads();

    // ================= P4: att = P @ V' =================
    if (wave < 8) {
        const int tb = wave * 16;
        f32x4 acc = {0,0,0,0};
        #pragma unroll
        for (int ks = 0; ks < 4; ++ks) {
            const int fo = ks*64 + lh*16;
            int soff = ((ks*4 + lh) ^ lr) << 4;
            bf16x8 a = *(const bf16x8*)(smem + FT_OFF + (tb + lr)*272 + fo);
            bf16x8 bv = *(const bf16x8*)(smem + VT_OFF + lr*256 + soff);
            acc = __builtin_amdgcn_mfma_f32_16x16x32_bf16(a, bv, acc, 0, 0, 0);
        }
        if (lr < 8) {
            float ob = out_b[g*EO_ + lr];
            #pragma unroll
            for (int reg = 0; reg < 4; ++reg) {
                int n = tb + lh*4 + reg;
                att[((size_t)(b*FN_ + n)*C_ + c)*FC_ + g*EO_ + lr] = acc[reg] + ob;
            }
        }
    }
}

// ============ final: 8 items/block, 32 lanes/item ============
__global__ __launch_bounds__(256) void k_final(const float* __restrict__ emb_feat,
                                               const float* __restrict__ att,
                                               const float* __restrict__ logit_w,
                                               const float* __restrict__ logit_b,
                                               const float* __restrict__ sorted_score,
                                               float* __restrict__ out)
{
    __shared__ float lwL[FC_*NT_ + NT_];
    const int t = threadIdx.x;
    for (int i = t; i < FC_*NT_ + NT_; i += 256)
        lwL[i] = (i < FC_*NT_) ? logit_w[i] : logit_b[i - FC_*NT_];
    __syncthreads();
    const int item = blockIdx.x*8 + (t >> 5);
    const int l = t & 31;
    const int d0 = l*4;
    float4 ev = *(const float4*)(emb_feat + (size_t)item*FC_ + d0);
    float4 av = *(const float4*)(att + (size_t)item*FC_ + d0);
    float a0 = fmaxf(ev.x + av.x, 0.f);
    float a1 = fmaxf(ev.y + av.y, 0.f);
    float a2 = fmaxf(ev.z + av.z, 0.f);
    float a3 = fmaxf(ev.w + av.w, 0.f);
    float s0 = a0*lwL[(d0+0)*NT_+0] + a1*lwL[(d0+1)*NT_+0] + a2*lwL[(d0+2)*NT_+0] + a3*lwL[(d0+3)*NT_+0];
    float s1 = a0*lwL[(d0+0)*NT_+1] + a1*lwL[(d0+1)*NT_+1] + a2*lwL[(d0+2)*NT_+1] + a3*lwL[(d0+3)*NT_+1];
    float s2 = a0*lwL[(d0+0)*NT_+2] + a1*lwL[(d0+1)*NT_+2] + a2*lwL[(d0+2)*NT_+2] + a3*lwL[(d0+3)*NT_+2];
    #pragma unroll
    for (int s = 1; s < 32; s <<= 1) {
        s0 += __shfl_xor(s0, s, 32);
        s1 += __shfl_xor(s1, s, 32);
        s2 += __shfl_xor(s2, s, 32);
    }
    if (l < NT_) {
        float lg = (l == 0) ? s0 : (l == 1) ? s1 : s2;
        lg += lwL[FC_*NT_ + l];
        float sg = 1.f / (1.f + expf(-lg));
        out[(size_t)item*NT_ + l] = sg * sorted_score[item];
    }
}

extern "C" void kernel_launch(void* const* d_in, const int* in_sizes, int n_in,
                              void* d_out, int out_size, void* d_ws, size_t ws_size,
                              hipStream_t stream) {
    (void)in_sizes; (void)n_in; (void)out_size; (void)ws_size;
    const float* roi_feat = (const float*)d_in[0];
    const float* scores   = (const float*)d_in[1];
    const float* pdeltas  = (const float*)d_in[2];
    const float* pboxes   = (const float*)d_in[3];
    const float* roi_w    = (const float*)d_in[4];
    const float* roi_b    = (const float*)d_in[5];
    const float* rank_w   = (const float*)d_in[6];
    const float* rank_b   = (const float*)d_in[7];
    const float* logit_w  = (const float*)d_in[8];
    const float* logit_b  = (const float*)d_in[9];
    const float* pos_w    = (const float*)d_in[10];
    const float* pos_b    = (const float*)d_in[11];
    const float* q_w      = (const float*)d_in[12];
    const float* q_b      = (const float*)d_in[13];
    const float* k_w      = (const float*)d_in[14];
    const float* k_b      = (const float*)d_in[15];
    const float* out_w    = (const float*)d_in[16];
    const float* out_b    = (const float*)d_in[17];
    float* ws = (float*)d_ws;

    float* roiP         = ws + O_ROIP;
    float* rankP        = ws + O_RANKP;
    int*   rank_idx     = (int*)(ws + O_RANKIDX);
    float* sorted_score = ws + O_SSCORE;
    float* sorted_boxes = ws + O_SBOX;
    float* emb_feat     = ws + O_EMB;
    float* att          = ws + O_ATT;
    unsigned short* lwb = (unsigned short*)(ws + O_LW);
    unsigned short* wtb = (unsigned short*)(ws + O_WT);
    unsigned short* embB = (unsigned short*)(ws + O_EMBB);

    k_embed<<<dim3(304), dim3(256), 0, stream>>>(roi_feat, roi_w, roi_b, rank_w, rank_b,
                                                 q_w, k_w, out_w, roiP, rankP, wtb);
    k_topk<<<dim3(B_*C_), dim3(512), 0, stream>>>(scores, rank_idx, sorted_score);
    k_gather<<<dim3(B_*FN_*C_/8), dim3(256), 0, stream>>>(rank_idx, roiP, rankP,
                                                          pdeltas, pboxes, emb_feat, embB, sorted_boxes);
    k_pos2<<<dim3(B_*C_*64), dim3(256), 0, stream>>>(sorted_boxes, pos_w, pos_b, lwb);
    k_attn<<<dim3(B_*C_*G_), dim3(1024), 0, stream>>>(embB, wtb, q_b, k_b, out_b, lwb, att);
    k_final<<<dim3(B_*FN_*C_/8), dim3(256), 0, stream>>>(emb_feat, att, logit_w, logit_b,
                                                         sorted_score, d_out ? (float*)d_out : nullptr);
}

// Round 13
// 183.648 us; speedup vs baseline: 1.0659x; 1.0127x over previous
//
#include <hip/hip_runtime.h>
#include <math.h>

#define B_    2
#define NB_   512
#define C_    80
#define FEAT_ 1024
#define FN_   128
#define FC_   128
#define PE_   64
#define G_    16
#define DQ_   64
#define EO_   8
#define NT_   3
#define SCALE_CLAMP_ 4.135166556742356f

typedef __attribute__((ext_vector_type(8))) short bf16x8;
typedef __attribute__((ext_vector_type(4))) float f32x4;

// ---- workspace layout (float offsets) ----
#define O_ROIP    ((size_t)0)                                   // 4*1024*128 (K-quarter partials)
#define O_RANKP   (O_ROIP + (size_t)4*B_*NB_*FC_)               // 4*128*128
#define O_RANKIDX (O_RANKP + (size_t)4*FN_*FC_)                 // B*128*80 (int)
#define O_SSCORE  (O_RANKIDX + (size_t)B_*FN_*C_)               // B*128*80
#define O_SBOX    (O_SSCORE + (size_t)B_*FN_*C_)                // B*128*80*4
#define O_EMB     (O_SBOX + (size_t)B_*FN_*C_*4)                // B*128*80*128
#define O_ATT     (O_EMB + (size_t)B_*FN_*C_*FC_)               // B*128*80*128
#define O_LW      (O_ATT + (size_t)B_*FN_*C_*FC_)               // 2*80*128*16*128 f16 = 84MB (log w)
#define O_WT      (O_LW + (size_t)B_*C_*FN_*G_*FN_/2)           // 16*144*128 bf16
#define O_EMBB    (O_WT + (size_t)16*144*128/2)                 // B*128*80*128 bf16

__device__ __forceinline__ float bf2f(unsigned short u) {
    return __uint_as_float(((unsigned int)u) << 16);
}
__device__ __forceinline__ unsigned short f2bf(float f) {
    unsigned int x = __float_as_uint(f);
    unsigned int r = (x + 0x7fff + ((x >> 16) & 1)) >> 16;   // RNE
    return (unsigned short)r;
}
__device__ __forceinline__ unsigned short f2h(float x) {
    _Float16 h = (_Float16)x;
    return __builtin_bit_cast(unsigned short, h);
}
__device__ __forceinline__ float h2f(unsigned short u) {
    _Float16 h = __builtin_bit_cast(_Float16, u);
    return (float)h;
}

// 16B-granule swizzle, 128B row (8 granules)
#define ADDR128(row, gr)  ((row)*128 + ((((gr) ^ ((row)&7))) << 4))

// ============ embed GEMMs (blocks 0..287: 72 row-tiles x 4 K-quarters) + WT prep (288..303) ============
__global__ __launch_bounds__(256) void k_embed(const float* __restrict__ roi_feat,
                                               const float* __restrict__ roi_w,
                                               const float* __restrict__ roi_b,
                                               const float* __restrict__ rank_w,
                                               const float* __restrict__ rank_b,
                                               const float* __restrict__ q_w,
                                               const float* __restrict__ k_w,
                                               const float* __restrict__ out_w,
                                               float* __restrict__ roiP,
                                               float* __restrict__ rankP,
                                               unsigned short* __restrict__ wtg)
{
    const int bid = blockIdx.x;
    const int t = threadIdx.x;
    if (bid >= 288) {
        // ---- WT prep: WT[g][144][128] bf16 (Wq^T | Wk^T | Wo^T | zeros)
        const int g = bid - 288;
        for (int idx = t; idx < 144*16; idx += 256) {
            const int row = idx >> 4;
            const int kc  = (idx & 15) * 8;
            unsigned short u[8];
            if (row < 64) {
                #pragma unroll
                for (int j = 0; j < 8; ++j) u[j] = f2bf(q_w[(size_t)(kc + j)*1024 + g*DQ_ + row]);
            } else if (row < 128) {
                const int r = row - 64;
                #pragma unroll
                for (int j = 0; j < 8; ++j) u[j] = f2bf(k_w[(size_t)(kc + j)*1024 + g*DQ_ + r]);
            } else if (row < 136) {
                const int e = row - 128;
                #pragma unroll
                for (int j = 0; j < 8; ++j) u[j] = f2bf(out_w[(size_t)g*FC_*EO_ + (size_t)(kc + j)*EO_ + e]);
            } else {
                #pragma unroll
                for (int j = 0; j < 8; ++j) u[j] = 0;
            }
            *(uint4*)(wtg + (size_t)g*144*128 + row*128 + kc) =
                make_uint4((unsigned)u[0] | ((unsigned)u[1] << 16),
                           (unsigned)u[2] | ((unsigned)u[3] << 16),
                           (unsigned)u[4] | ((unsigned)u[5] << 16),
                           (unsigned)u[6] | ((unsigned)u[7] << 16));
        }
        return;
    }
    const int kq  = bid & 3;
    const int rt  = bid >> 2;            // 0..71
    const bool isRank = rt >= 64;
    const int row0 = (isRank ? rt - 64 : rt) * 16;
    const int w = t >> 6, lane = t & 63, lr = lane & 15, lh = lane >> 4;
    const int col0 = w * 32;
    const float* W = isRank ? rank_w : roi_w;
    const float* bias = isRank ? rank_b : roi_b;

    const int arow = row0 + lr;
    f32x4 acc0 = {0,0,0,0}, acc1 = {0,0,0,0};

    #pragma unroll 4
    for (int ks = 0; ks < 8; ++ks) {
        const int kb = kq*256 + ks*32 + lh*8;
        bf16x8 af;
        if (!isRank) {
            float4 a0 = *(const float4*)(roi_feat + (size_t)arow*FEAT_ + kb);
            float4 a1 = *(const float4*)(roi_feat + (size_t)arow*FEAT_ + kb + 4);
            af[0] = (short)f2bf(a0.x); af[1] = (short)f2bf(a0.y);
            af[2] = (short)f2bf(a0.z); af[3] = (short)f2bf(a0.w);
            af[4] = (short)f2bf(a1.x); af[5] = (short)f2bf(a1.y);
            af[6] = (short)f2bf(a1.z); af[7] = (short)f2bf(a1.w);
        } else {
            #pragma unroll
            for (int j = 0; j < 8; ++j) {
                int k = kb + j;
                int kk = k & 511;
                float inv = exp2f(-(float)kk * 0.0194644226f);  // log2(1000)/512
                float arg = (float)arow * inv;
                float v = (k < 512) ? __sinf(arg) : __cosf(arg);
                af[j] = (short)f2bf(v);
            }
        }
        bf16x8 bf0, bf1;
        #pragma unroll
        for (int j = 0; j < 8; ++j) {
            const float* wr = W + (size_t)(kb + j)*FC_ + col0 + lr;
            bf0[j] = (short)f2bf(wr[0]);
            bf1[j] = (short)f2bf(wr[16]);
        }
        acc0 = __builtin_amdgcn_mfma_f32_16x16x32_bf16(af, bf0, acc0, 0, 0, 0);
        acc1 = __builtin_amdgcn_mfma_f32_16x16x32_bf16(af, bf1, acc1, 0, 0, 0);
    }
    float* dst = isRank ? (rankP + (size_t)kq*FN_*FC_) : (roiP + (size_t)kq*(B_*NB_)*FC_);
    #pragma unroll
    for (int tile = 0; tile < 2; ++tile) {
        f32x4 a = tile ? acc1 : acc0;
        int col = col0 + tile*16 + lr;
        float bv = (kq == 0) ? bias[col] : 0.0f;
        #pragma unroll
        for (int reg = 0; reg < 4; ++reg) {
            int rr = row0 + lh*4 + reg;
            dst[(size_t)rr*FC_ + col] = a[reg] + bv;
        }
    }
}

// ============ softmax over boxes + stable top-128 rank ============
__global__ __launch_bounds__(512) void k_topk(const float* __restrict__ scores,
                                              int* __restrict__ rank_idx,
                                              float* __restrict__ sorted_score)
{
    int b = blockIdx.x / C_, c = blockIdx.x % C_;
    __shared__ float p[NB_];
    __shared__ float red[NB_];
    int i = threadIdx.x;
    float s = scores[(size_t)(b*NB_ + i)*(C_+1) + c];
    red[i] = s; __syncthreads();
    for (int o = 256; o > 0; o >>= 1) { if (i < o) red[i] = fmaxf(red[i], red[i+o]); __syncthreads(); }
    float mx = red[0]; __syncthreads();
    float e = expf(s - mx);
    red[i] = e; __syncthreads();
    for (int o = 256; o > 0; o >>= 1) { if (i < o) red[i] += red[i+o]; __syncthreads(); }
    float sum = red[0]; __syncthreads();
    float pi = e / sum;
    p[i] = pi; __syncthreads();
    int rank = 0;
    for (int j4 = 0; j4 < NB_/4; ++j4) {
        float4 pj = *(const float4*)&p[j4*4];
        int j = j4*4;
        rank += (pj.x > pi) || (pj.x == pi && (j+0) < i);
        rank += (pj.y > pi) || (pj.y == pi && (j+1) < i);
        rank += (pj.z > pi) || (pj.z == pi && (j+2) < i);
        rank += (pj.w > pi) || (pj.w == pi && (j+3) < i);
    }
    if (rank < FN_) {
        rank_idx[(size_t)(b*FN_ + rank)*C_ + c] = i;
        sorted_score[(size_t)(b*FN_ + rank)*C_ + c] = pi;
    }
}

// ============ gather emb_feat (sum 4 K-quarter partials, +bf16 copy) + refined boxes ============
__global__ __launch_bounds__(256) void k_gather(const int* __restrict__ rank_idx,
                                                const float* __restrict__ roiP,
                                                const float* __restrict__ rankP,
                                                const float* __restrict__ pdeltas,
                                                const float* __restrict__ pboxes,
                                                float* __restrict__ emb_feat,
                                                unsigned short* __restrict__ embB,
                                                float* __restrict__ sorted_boxes)
{
    const int t = threadIdx.x;
    const int item = blockIdx.x*8 + (t >> 5);
    const int l = t & 31;
    const int c = item % C_;
    const int bn = item / C_;
    const int n = bn & (FN_-1);
    const int b = bn >> 7;
    const int idx = rank_idx[item];
    const int row = b*NB_ + idx;
    float4 sm = make_float4(0.f, 0.f, 0.f, 0.f);
    #pragma unroll
    for (int kq = 0; kq < 4; ++kq) {
        float4 e = *(const float4*)(roiP + (size_t)(kq*B_*NB_ + row)*FC_ + l*4);
        float4 r = *(const float4*)(rankP + (size_t)(kq*FN_ + n)*FC_ + l*4);
        sm.x += e.x + r.x; sm.y += e.y + r.y; sm.z += e.z + r.z; sm.w += e.w + r.w;
    }
    *(float4*)(emb_feat + (size_t)item*FC_ + l*4) = sm;
    *(uint2*)(embB + (size_t)item*FC_ + l*4) =
        make_uint2((unsigned)f2bf(sm.x) | ((unsigned)f2bf(sm.y) << 16),
                   (unsigned)f2bf(sm.z) | ((unsigned)f2bf(sm.w) << 16));
    if (l == 0) {
        float x1 = pboxes[row*4+0], y1 = pboxes[row*4+1], x2 = pboxes[row*4+2], y2 = pboxes[row*4+3];
        float w = x2 - x1, h = y2 - y1;
        float cx = x1 + 0.5f*w, cy = y1 + 0.5f*h;
        const float* dl = pdeltas + (size_t)row*(C_*4) + c*4;
        float dx = dl[0]/10.0f, dy = dl[1]/10.0f;
        float dw = fminf(dl[2]/5.0f, SCALE_CLAMP_);
        float dh = fminf(dl[3]/5.0f, SCALE_CLAMP_);
        float pcx = dx*w + cx, pcy = dy*h + cy;
        float pw = expf(dw)*w, ph = expf(dh)*h;
        float* ob = sorted_boxes + (size_t)item*4;
        ob[0] = pcx - 0.5f*pw; ob[1] = pcy - 0.5f*ph;
        ob[2] = pcx + 0.5f*pw; ob[3] = pcy + 0.5f*ph;
    }
}

// ============ prior via MFMA -> store f16(log w) ============
__global__ __launch_bounds__(256) void k_pos2(const float* __restrict__ sorted_boxes,
                                              const float* __restrict__ pos_w,
                                              const float* __restrict__ pos_b,
                                              unsigned short* __restrict__ lw)
{
    const int n2   = blockIdx.x & 63;
    const int rest = blockIdx.x >> 6;
    const int cl   = rest % C_;
    const int b    = rest / C_;
    const int n0   = n2 * 2;
    const int t    = threadIdx.x;

    __shared__ float geomL[FN_][6];               // 3 KB
    __shared__ unsigned short featL[256*PE_];     // 32 KB, swizzled 128B rows
    __shared__ unsigned short poswL[G_*PE_];      // 2 KB, swizzled 128B rows
    __shared__ float pbL[G_];
    __shared__ float sdimL[8];

    if (t < FN_) {
        const float* bx = sorted_boxes + (((size_t)(b*FN_ + t))*C_ + cl)*4;
        float x1 = bx[0], y1 = bx[1], x2 = bx[2], y2 = bx[3];
        float w = x2 - x1 + 1.0f;
        float h = y2 - y1 + 1.0f;
        geomL[t][0] = 0.5f*(x1+x2);
        geomL[t][1] = 0.5f*(y1+y2);
        geomL[t][2] = w;
        geomL[t][3] = h;
        geomL[t][4] = __logf(w);
        geomL[t][5] = __logf(h);
    } else {
        int id = t - 128;
        int g  = id >> 3;
        int gr = id & 7;
        unsigned short u[8];
        #pragma unroll
        for (int j = 0; j < 8; ++j) u[j] = f2bf(pos_w[(gr*8 + j)*G_ + g]);
        *(uint4*)((char*)poswL + ADDR128(g, gr)) =
            make_uint4((unsigned)u[0] | ((unsigned)u[1] << 16),
                       (unsigned)u[2] | ((unsigned)u[3] << 16),
                       (unsigned)u[4] | ((unsigned)u[5] << 16),
                       (unsigned)u[6] | ((unsigned)u[7] << 16));
    }
    if (t < G_) pbL[t] = pos_b[t];
    if (t >= 16 && t < 24) sdimL[t-16] = 1.0f / powf(1000.0f, 0.125f*(float)(t-16));
    __syncthreads();

    {
        const int nl = t >> 7;
        const int m  = t & 127;
        const int n  = n0 + nl;
        float pm[4];
        {
            float cxn = geomL[n][0], cyn = geomL[n][1];
            float rwn = 1.0f/geomL[n][2], rhn = 1.0f/geomL[n][3];
            pm[0] = __logf(fmaxf(fabsf((cxn - geomL[m][0]) * rwn), 1e-3f)) * 100.0f;
            pm[1] = __logf(fmaxf(fabsf((cyn - geomL[m][1]) * rhn), 1e-3f)) * 100.0f;
            pm[2] = (geomL[n][4] - geomL[m][4]) * 100.0f;
            pm[3] = (geomL[n][5] - geomL[m][5]) * 100.0f;
        }
        char* base = (char*)featL;
        #pragma unroll
        for (int f = 0; f < 4; ++f) {
            float s[8], c[8];
            #pragma unroll
            for (int r = 0; r < 8; ++r) {
                __sincosf(pm[f] * sdimL[r], &s[r], &c[r]);
            }
            unsigned short us[8], uc[8];
            #pragma unroll
            for (int r = 0; r < 8; ++r) { us[r] = f2bf(s[r]); uc[r] = f2bf(c[r]); }
            *(uint4*)(base + ADDR128(t, 2*f)) =
                make_uint4((unsigned)us[0] | ((unsigned)us[1] << 16),
                           (unsigned)us[2] | ((unsigned)us[3] << 16),
                           (unsigned)us[4] | ((unsigned)us[5] << 16),
                           (unsigned)us[6] | ((unsigned)us[7] << 16));
            *(uint4*)(base + ADDR128(t, 2*f + 1)) =
                make_uint4((unsigned)uc[0] | ((unsigned)uc[1] << 16),
                           (unsigned)uc[2] | ((unsigned)uc[3] << 16),
                           (unsigned)uc[4] | ((unsigned)uc[5] << 16),
                           (unsigned)uc[6] | ((unsigned)uc[7] << 16));
        }
    }
    __syncthreads();

    {
        const int wave = t >> 6, lane = t & 63;
        const int lr = lane & 15, lh = lane >> 4;
        const float pbg = pbL[lr];           // g = lr
        #pragma unroll
        for (int ti = 0; ti < 4; ++ti) {
            const int t16 = wave*4 + ti;
            f32x4 acc = {0,0,0,0};
            #pragma unroll
            for (int ks = 0; ks < 2; ++ks) {
                bf16x8 a  = *(const bf16x8*)((char*)featL + ADDR128(t16*16 + lr, ks*4 + lh));
                bf16x8 bb = *(const bf16x8*)((char*)poswL + ADDR128(lr, ks*4 + lh));
                acc = __builtin_amdgcn_mfma_f32_16x16x32_bf16(a, bb, acc, 0, 0, 0);
            }
            const int g = lr;
            #pragma unroll
            for (int reg = 0; reg < 4; ++reg) {
                int p = t16*16 + lh*4 + reg;
                int n = n0 + (p >> 7);
                int m = p & 127;
                float w = fmaxf(fmaxf(acc[reg] + pbg, 0.0f), 1e-6f);
                lw[(((size_t)(b*C_ + cl)*FN_ + n)*G_ + g)*FN_ + m] = f2h(__logf(w));
            }
        }
    }
}

// ============ MFMA attention per (batch, class, group) — 70.5 KB LDS ============
// region FT (34816 B, rows stride 272B): ft bf16 -> aff f16 -> P bf16
#define FT_OFF   0
#define QL_OFF   34816    // q bf16 [128n][64dq] swz 16 KB
#define KL_OFF   51200    // k bf16 [128m][64dq] swz 16 KB
#define VT_OFF   67584    // V'^T bf16 [16e][128m] swz 4 KB
#define BIAS_OFF 71680    // 128 f32
#define SMEM_SZ  72192

__global__ __launch_bounds__(1024, 8) void k_attn(const unsigned short* __restrict__ embB,
                                               const unsigned short* __restrict__ wt,
                                               const float* __restrict__ q_b,
                                               const float* __restrict__ k_b,
                                               const float* __restrict__ out_b,
                                               const unsigned short* __restrict__ lw,
                                               float* __restrict__ att)
{
    const int g    = blockIdx.x & 15;
    const int rest = blockIdx.x >> 4;
    const int cl   = rest % C_;
    const int b    = rest / C_;
    const int c    = cl;
    const int t  = threadIdx.x;
    const int wave = t >> 6;
    const int lane = t & 63;
    const int lr = lane & 15;
    const int lh = lane >> 4;              // 0..3

    __shared__ char smem[SMEM_SZ];
    float* biasL = (float*)(smem + BIAS_OFF);

    // ================= P0: staging (ft copy bf16 + VT-zero + bias) =================
    {
        const char* src = (const char*)embB + ((size_t)(b*FN_)*C_ + c)*FC_*2;
        #pragma unroll
        for (int s = 0; s < 2; ++s) {
            int fi = t + s*1024;
            int n  = fi >> 4;
            int o16 = (fi & 15) * 16;
            uint4 v = *(const uint4*)(src + (size_t)n*C_*FC_*2 + o16);
            *(uint4*)(smem + FT_OFF + n*272 + o16) = v;
        }
    }
    if (t >= 512 && t < 768) {
        int i = t - 512;
        *(uint2*)(smem + VT_OFF + 8*256 + i*8) = make_uint2(0u, 0u);
    }
    if (t >= 128 && t < 256) {
        int r = t - 128;
        biasL[r] = (r < 64) ? q_b[g*DQ_ + r] : k_b[g*DQ_ + (r-64)];
    }
    __syncthreads();

    // ================= P1: proj MFMA (A from pre-transposed bf16 WT) =================
    {
        const int rb = (wave >> 2) * 32;
        const int nb = (wave & 3) * 32;
        const char* wtg = (const char*)wt + (size_t)g*144*256;
        f32x4 acc00 = {0,0,0,0}, acc01 = {0,0,0,0}, acc10 = {0,0,0,0}, acc11 = {0,0,0,0};
        f32x4 accV  = {0,0,0,0};
        #pragma unroll
        for (int ks = 0; ks < 4; ++ks) {
            const int fo = ks*64 + lh*16;
            bf16x8 a0 = *(const bf16x8*)(wtg + (rb + lr)*256 + fo);
            bf16x8 a1 = *(const bf16x8*)(wtg + (rb + 16 + lr)*256 + fo);
            bf16x8 b0 = *(const bf16x8*)(smem + FT_OFF + (nb + lr)*272 + fo);
            bf16x8 b1 = *(const bf16x8*)(smem + FT_OFF + (nb + 16 + lr)*272 + fo);
            acc00 = __builtin_amdgcn_mfma_f32_16x16x32_bf16(a0, b0, acc00, 0, 0, 0);
            acc01 = __builtin_amdgcn_mfma_f32_16x16x32_bf16(a0, b1, acc01, 0, 0, 0);
            acc10 = __builtin_amdgcn_mfma_f32_16x16x32_bf16(a1, b0, acc10, 0, 0, 0);
            acc11 = __builtin_amdgcn_mfma_f32_16x16x32_bf16(a1, b1, acc11, 0, 0, 0);
            if (wave < 8) {
                bf16x8 av = *(const bf16x8*)(wtg + (128 + lr)*256 + fo);
                bf16x8 bv = *(const bf16x8*)(smem + FT_OFF + (wave*16 + lr)*272 + fo);
                accV = __builtin_amdgcn_mfma_f32_16x16x32_bf16(av, bv, accV, 0, 0, 0);
            }
        }
        #pragma unroll
        for (int ti = 0; ti < 2; ++ti) {
            #pragma unroll
            for (int tj = 0; tj < 2; ++tj) {
                f32x4 a = (ti == 0) ? (tj == 0 ? acc00 : acc01) : (tj == 0 ? acc10 : acc11);
                int r0 = rb + ti*16 + lh*4;
                int n  = nb + tj*16 + lr;
                float v0 = a[0] + biasL[r0+0];
                float v1 = a[1] + biasL[r0+1];
                float v2 = a[2] + biasL[r0+2];
                float v3 = a[3] + biasL[r0+3];
                int dq0 = r0 & 63;
                int off = (r0 < 64 ? QL_OFF : KL_OFF);
                char* dst = smem + off + ADDR128(n, dq0 >> 3) + ((dq0 >> 2) & 1)*8;
                *(uint2*)dst = make_uint2((unsigned)f2bf(v0) | ((unsigned)f2bf(v1) << 16),
                                          (unsigned)f2bf(v2) | ((unsigned)f2bf(v3) << 16));
            }
        }
        if (wave < 8 && lh < 2) {
            int m = wave*16 + lr;
            #pragma unroll
            for (int reg = 0; reg < 4; ++reg) {
                int e = lh*4 + reg;
                char* dst = smem + VT_OFF + (e)*256 + ((((m >> 3) ^ e)) << 4) + (m & 7)*2;
                *(unsigned short*)dst = f2bf(accV[reg]);
            }
        }
    }
    __syncthreads();

    // ================= P2: issue lw loads (T14 async-split; consumed in P3,
    //                  latency hidden under P2 MFMA, drained at the P2->P3 barrier),
    //                  then aff MFMA -> f16 into FT region (ft is dead) =================
    uint4 gl0, gl1;
    {
        const int row_p = t >> 3;
        const int lp_p  = t & 7;
        const unsigned short* lwrow = lw + ((((size_t)(b*C_ + cl))*FN_ + row_p)*G_ + g)*FN_ + lp_p*16;
        gl0 = *(const uint4*)(lwrow);
        gl1 = *(const uint4*)(lwrow + 8);
    }
    {
        const int nb = (wave >> 2) * 32;
        const int mb = (wave & 3) * 32;
        f32x4 acc00 = {0,0,0,0}, acc01 = {0,0,0,0}, acc10 = {0,0,0,0}, acc11 = {0,0,0,0};
        #pragma unroll
        for (int ks = 0; ks < 2; ++ks) {
            int soff = ((ks*4 + lh) ^ (lr & 7)) << 4;
            bf16x8 a0 = *(const bf16x8*)(smem + QL_OFF + (nb + lr)*128 + soff);
            bf16x8 a1 = *(const bf16x8*)(smem + QL_OFF + (nb + 16 + lr)*128 + soff);
            bf16x8 b0 = *(const bf16x8*)(smem + KL_OFF + (mb + lr)*128 + soff);
            bf16x8 b1 = *(const bf16x8*)(smem + KL_OFF + (mb + 16 + lr)*128 + soff);
            acc00 = __builtin_amdgcn_mfma_f32_16x16x32_bf16(a0, b0, acc00, 0, 0, 0);
            acc01 = __builtin_amdgcn_mfma_f32_16x16x32_bf16(a0, b1, acc01, 0, 0, 0);
            acc10 = __builtin_amdgcn_mfma_f32_16x16x32_bf16(a1, b0, acc10, 0, 0, 0);
            acc11 = __builtin_amdgcn_mfma_f32_16x16x32_bf16(a1, b1, acc11, 0, 0, 0);
        }
        #pragma unroll
        for (int ti = 0; ti < 2; ++ti) {
            #pragma unroll
            for (int tj = 0; tj < 2; ++tj) {
                f32x4 a = (ti == 0) ? (tj == 0 ? acc00 : acc01) : (tj == 0 ? acc10 : acc11);
                int n0 = nb + ti*16 + lh*4;
                int m  = mb + tj*16 + lr;
                #pragma unroll
                for (int reg = 0; reg < 4; ++reg)
                    *(unsigned short*)(smem + FT_OFF + (n0 + reg)*272 + 2*m) = f2h(a[reg]);
            }
        }
    }
    __syncthreads();

    // ================= P3: softmax (aff f16 LDS + prefetched lw regs) -> P bf16 in place =================
    {
        const int row = t >> 3;
        const int lp  = t & 7;
        char* abase = smem + FT_OFF + row*272 + lp*32;
        uint4 af0 = *(const uint4*)abase;
        uint4 af1 = *(const uint4*)(abase + 16);
        const unsigned short* ah0 = (const unsigned short*)&af0;
        const unsigned short* ah1 = (const unsigned short*)&af1;
        const unsigned short* lp0 = (const unsigned short*)&gl0;
        const unsigned short* lp1 = (const unsigned short*)&gl1;
        float v[16];
        float mx = -INFINITY;
        #pragma unroll
        for (int j = 0; j < 8; ++j) {
            float val = h2f(ah0[j])*0.125f + h2f(lp0[j]);
            v[j] = val; mx = fmaxf(mx, val);
        }
        #pragma unroll
        for (int j = 0; j < 8; ++j) {
            float val = h2f(ah1[j])*0.125f + h2f(lp1[j]);
            v[8+j] = val; mx = fmaxf(mx, val);
        }
        #pragma unroll
        for (int s = 1; s < 8; s <<= 1) mx = fmaxf(mx, __shfl_xor(mx, s, 8));
        float sum = 0.f;
        #pragma unroll
        for (int j = 0; j < 16; ++j) { v[j] = __expf(v[j] - mx); sum += v[j]; }
        #pragma unroll
        for (int s = 1; s < 8; s <<= 1) sum += __shfl_xor(sum, s, 8);
        float rs = 1.0f / sum;
        unsigned short u[16];
        #pragma unroll
        for (int j = 0; j < 16; ++j) u[j] = f2bf(v[j] * rs);
        *(uint4*)abase = make_uint4((unsigned)u[0] | ((unsigned)u[1] << 16),
                                    (unsigned)u[2] | ((unsigned)u[3] << 16),
                                    (unsigned)u[4] | ((unsigned)u[5] << 16),
                                    (unsigned)u[6] | ((unsigned)u[7] << 16));
        *(uint4*)(abase + 16) = make_uint4((unsigned)u[8]  | ((unsigned)u[9]  << 16),
                                           (unsigned)u[10] | ((unsigned)u[11] << 16),
                                           (unsigned)u[12] | ((unsigned)u[13] << 16),
                                           (unsigned)u[14] | ((unsigned)u[15] << 16));
    }
    __syncthreads();

    // ================= P4: att = P @ V' =================
    if (wave < 8) {
        const int tb = wave * 16;
        f32x4 acc = {0,0,0,0};
        #pragma unroll
        for (int ks = 0; ks < 4; ++ks) {
            const int fo = ks*64 + lh*16;
            int soff = ((ks*4 + lh) ^ lr) << 4;
            bf16x8 a = *(const bf16x8*)(smem + FT_OFF + (tb + lr)*272 + fo);
            bf16x8 bv = *(const bf16x8*)(smem + VT_OFF + lr*256 + soff);
            acc = __builtin_amdgcn_mfma_f32_16x16x32_bf16(a, bv, acc, 0, 0, 0);
        }
        if (lr < 8) {
            float ob = out_b[g*EO_ + lr];
            #pragma unroll
            for (int reg = 0; reg < 4; ++reg) {
                int n = tb + lh*4 + reg;
                att[((size_t)(b*FN_ + n)*C_ + c)*FC_ + g*EO_ + lr] = acc[reg] + ob;
            }
        }
    }
}

// ============ final: 8 items/block, 32 lanes/item ============
__global__ __launch_bounds__(256) void k_final(const float* __restrict__ emb_feat,
                                               const float* __restrict__ att,
                                               const float* __restrict__ logit_w,
                                               const float* __restrict__ logit_b,
                                               const float* __restrict__ sorted_score,
                                               float* __restrict__ out)
{
    __shared__ float lwL[FC_*NT_ + NT_];
    const int t = threadIdx.x;
    for (int i = t; i < FC_*NT_ + NT_; i += 256)
        lwL[i] = (i < FC_*NT_) ? logit_w[i] : logit_b[i - FC_*NT_];
    __syncthreads();
    const int item = blockIdx.x*8 + (t >> 5);
    const int l = t & 31;
    const int d0 = l*4;
    float4 ev = *(const float4*)(emb_feat + (size_t)item*FC_ + d0);
    float4 av = *(const float4*)(att + (size_t)item*FC_ + d0);
    float a0 = fmaxf(ev.x + av.x, 0.f);
    float a1 = fmaxf(ev.y + av.y, 0.f);
    float a2 = fmaxf(ev.z + av.z, 0.f);
    float a3 = fmaxf(ev.w + av.w, 0.f);
    float s0 = a0*lwL[(d0+0)*NT_+0] + a1*lwL[(d0+1)*NT_+0] + a2*lwL[(d0+2)*NT_+0] + a3*lwL[(d0+3)*NT_+0];
    float s1 = a0*lwL[(d0+0)*NT_+1] + a1*lwL[(d0+1)*NT_+1] + a2*lwL[(d0+2)*NT_+1] + a3*lwL[(d0+3)*NT_+1];
    float s2 = a0*lwL[(d0+0)*NT_+2] + a1*lwL[(d0+1)*NT_+2] + a2*lwL[(d0+2)*NT_+2] + a3*lwL[(d0+3)*NT_+2];
    #pragma unroll
    for (int s = 1; s < 32; s <<= 1) {
        s0 += __shfl_xor(s0, s, 32);
        s1 += __shfl_xor(s1, s, 32);
        s2 += __shfl_xor(s2, s, 32);
    }
    if (l < NT_) {
        float lg = (l == 0) ? s0 : (l == 1) ? s1 : s2;
        lg += lwL[FC_*NT_ + l];
        float sg = 1.f / (1.f + expf(-lg));
        out[(size_t)item*NT_ + l] = sg * sorted_score[item];
    }
}

extern "C" void kernel_launch(void* const* d_in, const int* in_sizes, int n_in,
                              void* d_out, int out_size, void* d_ws, size_t ws_size,
                              hipStream_t stream) {
    (void)in_sizes; (void)n_in; (void)out_size; (void)ws_size;
    const float* roi_feat = (const float*)d_in[0];
    const float* scores   = (const float*)d_in[1];
    const float* pdeltas  = (const float*)d_in[2];
    const float* pboxes   = (const float*)d_in[3];
    const float* roi_w    = (const float*)d_in[4];
    const float* roi_b    = (const float*)d_in[5];
    const float* rank_w   = (const float*)d_in[6];
    const float* rank_b   = (const float*)d_in[7];
    const float* logit_w  = (const float*)d_in[8];
    const float* logit_b  = (const float*)d_in[9];
    const float* pos_w    = (const float*)d_in[10];
    const float* pos_b    = (const float*)d_in[11];
    const float* q_w      = (const float*)d_in[12];
    const float* q_b      = (const float*)d_in[13];
    const float* k_w      = (const float*)d_in[14];
    const float* k_b      = (const float*)d_in[15];
    const float* out_w    = (const float*)d_in[16];
    const float* out_b    = (const float*)d_in[17];
    float* ws = (float*)d_ws;

    float* roiP         = ws + O_ROIP;
    float* rankP        = ws + O_RANKP;
    int*   rank_idx     = (int*)(ws + O_RANKIDX);
    float* sorted_score = ws + O_SSCORE;
    float* sorted_boxes = ws + O_SBOX;
    float* emb_feat     = ws + O_EMB;
    float* att          = ws + O_ATT;
    unsigned short* lwb = (unsigned short*)(ws + O_LW);
    unsigned short* wtb = (unsigned short*)(ws + O_WT);
    unsigned short* embB = (unsigned short*)(ws + O_EMBB);

    k_embed<<<dim3(304), dim3(256), 0, stream>>>(roi_feat, roi_w, roi_b, rank_w, rank_b,
                                                 q_w, k_w, out_w, roiP, rankP, wtb);
    k_topk<<<dim3(B_*C_), dim3(512), 0, stream>>>(scores, rank_idx, sorted_score);
    k_gather<<<dim3(B_*FN_*C_/8), dim3(256), 0, stream>>>(rank_idx, roiP, rankP,
                                                          pdeltas, pboxes, emb_feat, embB, sorted_boxes);
    k_pos2<<<dim3(B_*C_*64), dim3(256), 0, stream>>>(sorted_boxes, pos_w, pos_b, lwb);
    k_attn<<<dim3(B_*C_*G_), dim3(1024), 0, stream>>>(embB, wtb, q_b, k_b, out_b, lwb, att);
    k_final<<<dim3(B_*FN_*C_/8), dim3(256), 0, stream>>>(emb_feat, att, logit_w, logit_b,
                                                         sorted_score, d_out ? (float*)d_out : nullptr);
}

// Round 14
// 182.524 us; speedup vs baseline: 1.0724x; 1.0062x over previous
//
#include <hip/hip_runtime.h>
#include <math.h>

#define B_    2
#define NB_   512
#define C_    80
#define FEAT_ 1024
#define FN_   128
#define FC_   128
#define PE_   64
#define G_    16
#define DQ_   64
#define EO_   8
#define NT_   3
#define SCALE_CLAMP_ 4.135166556742356f

typedef __attribute__((ext_vector_type(8))) short bf16x8;
typedef __attribute__((ext_vector_type(4))) float f32x4;

// ---- workspace layout (float offsets) ----
#define O_ROIP    ((size_t)0)                                   // 4*1024*128 (K-quarter partials)
#define O_RANKP   (O_ROIP + (size_t)4*B_*NB_*FC_)               // 4*128*128
#define O_SSCORE  (O_RANKP + (size_t)4*FN_*FC_)                 // B*128*80
#define O_SBOX    (O_SSCORE + (size_t)B_*FN_*C_)                // B*128*80*4
#define O_EMB     (O_SBOX + (size_t)B_*FN_*C_*4)                // B*128*80*128
#define O_ATT     (O_EMB + (size_t)B_*FN_*C_*FC_)               // B*128*80*128
#define O_LW      (O_ATT + (size_t)B_*FN_*C_*FC_)               // 2*80*128*16*128 f16 = 84MB (log w)
#define O_WT      (O_LW + (size_t)B_*C_*FN_*G_*FN_/2)           // 16*144*128 bf16
#define O_EMBB    (O_WT + (size_t)16*144*128/2)                 // B*128*80*128 bf16

__device__ __forceinline__ float bf2f(unsigned short u) {
    return __uint_as_float(((unsigned int)u) << 16);
}
__device__ __forceinline__ unsigned short f2bf(float f) {
    unsigned int x = __float_as_uint(f);
    unsigned int r = (x + 0x7fff + ((x >> 16) & 1)) >> 16;   // RNE
    return (unsigned short)r;
}
__device__ __forceinline__ unsigned short f2h(float x) {
    _Float16 h = (_Float16)x;
    return __builtin_bit_cast(unsigned short, h);
}
__device__ __forceinline__ float h2f(unsigned short u) {
    _Float16 h = __builtin_bit_cast(_Float16, u);
    return (float)h;
}

// 16B-granule swizzle, 128B row (8 granules)
#define ADDR128(row, gr)  ((row)*128 + ((((gr) ^ ((row)&7))) << 4))

// ============ embed GEMMs (blocks 0..287: 72 row-tiles x 4 K-quarters) + WT prep (288..303) ============
__global__ __launch_bounds__(256) void k_embed(const float* __restrict__ roi_feat,
                                               const float* __restrict__ roi_w,
                                               const float* __restrict__ roi_b,
                                               const float* __restrict__ rank_w,
                                               const float* __restrict__ rank_b,
                                               const float* __restrict__ q_w,
                                               const float* __restrict__ k_w,
                                               const float* __restrict__ out_w,
                                               float* __restrict__ roiP,
                                               float* __restrict__ rankP,
                                               unsigned short* __restrict__ wtg)
{
    const int bid = blockIdx.x;
    const int t = threadIdx.x;
    if (bid >= 288) {
        const int g = bid - 288;
        for (int idx = t; idx < 144*16; idx += 256) {
            const int row = idx >> 4;
            const int kc  = (idx & 15) * 8;
            unsigned short u[8];
            if (row < 64) {
                #pragma unroll
                for (int j = 0; j < 8; ++j) u[j] = f2bf(q_w[(size_t)(kc + j)*1024 + g*DQ_ + row]);
            } else if (row < 128) {
                const int r = row - 64;
                #pragma unroll
                for (int j = 0; j < 8; ++j) u[j] = f2bf(k_w[(size_t)(kc + j)*1024 + g*DQ_ + r]);
            } else if (row < 136) {
                const int e = row - 128;
                #pragma unroll
                for (int j = 0; j < 8; ++j) u[j] = f2bf(out_w[(size_t)g*FC_*EO_ + (size_t)(kc + j)*EO_ + e]);
            } else {
                #pragma unroll
                for (int j = 0; j < 8; ++j) u[j] = 0;
            }
            *(uint4*)(wtg + (size_t)g*144*128 + row*128 + kc) =
                make_uint4((unsigned)u[0] | ((unsigned)u[1] << 16),
                           (unsigned)u[2] | ((unsigned)u[3] << 16),
                           (unsigned)u[4] | ((unsigned)u[5] << 16),
                           (unsigned)u[6] | ((unsigned)u[7] << 16));
        }
        return;
    }
    const int kq  = bid & 3;
    const int rt  = bid >> 2;            // 0..71
    const bool isRank = rt >= 64;
    const int row0 = (isRank ? rt - 64 : rt) * 16;
    const int w = t >> 6, lane = t & 63, lr = lane & 15, lh = lane >> 4;
    const int col0 = w * 32;
    const float* W = isRank ? rank_w : roi_w;
    const float* bias = isRank ? rank_b : roi_b;

    const int arow = row0 + lr;
    f32x4 acc0 = {0,0,0,0}, acc1 = {0,0,0,0};

    #pragma unroll 4
    for (int ks = 0; ks < 8; ++ks) {
        const int kb = kq*256 + ks*32 + lh*8;
        bf16x8 af;
        if (!isRank) {
            float4 a0 = *(const float4*)(roi_feat + (size_t)arow*FEAT_ + kb);
            float4 a1 = *(const float4*)(roi_feat + (size_t)arow*FEAT_ + kb + 4);
            af[0] = (short)f2bf(a0.x); af[1] = (short)f2bf(a0.y);
            af[2] = (short)f2bf(a0.z); af[3] = (short)f2bf(a0.w);
            af[4] = (short)f2bf(a1.x); af[5] = (short)f2bf(a1.y);
            af[6] = (short)f2bf(a1.z); af[7] = (short)f2bf(a1.w);
        } else {
            #pragma unroll
            for (int j = 0; j < 8; ++j) {
                int k = kb + j;
                int kk = k & 511;
                float inv = exp2f(-(float)kk * 0.0194644226f);  // log2(1000)/512
                float arg = (float)arow * inv;
                float v = (k < 512) ? __sinf(arg) : __cosf(arg);
                af[j] = (short)f2bf(v);
            }
        }
        bf16x8 bf0, bf1;
        #pragma unroll
        for (int j = 0; j < 8; ++j) {
            const float* wr = W + (size_t)(kb + j)*FC_ + col0 + lr;
            bf0[j] = (short)f2bf(wr[0]);
            bf1[j] = (short)f2bf(wr[16]);
        }
        acc0 = __builtin_amdgcn_mfma_f32_16x16x32_bf16(af, bf0, acc0, 0, 0, 0);
        acc1 = __builtin_amdgcn_mfma_f32_16x16x32_bf16(af, bf1, acc1, 0, 0, 0);
    }
    float* dst = isRank ? (rankP + (size_t)kq*FN_*FC_) : (roiP + (size_t)kq*(B_*NB_)*FC_);
    #pragma unroll
    for (int tile = 0; tile < 2; ++tile) {
        f32x4 a = tile ? acc1 : acc0;
        int col = col0 + tile*16 + lr;
        float bv = (kq == 0) ? bias[col] : 0.0f;
        #pragma unroll
        for (int reg = 0; reg < 4; ++reg) {
            int rr = row0 + lh*4 + reg;
            dst[(size_t)rr*FC_ + col] = a[reg] + bv;
        }
    }
}

// ============ fused: per-(b,c) softmax + stable top-128 + gather + boxes ============
__global__ __launch_bounds__(512) void k_topkgather(const float* __restrict__ scores,
                                                    const float* __restrict__ roiP,
                                                    const float* __restrict__ rankP,
                                                    const float* __restrict__ pdeltas,
                                                    const float* __restrict__ pboxes,
                                                    float* __restrict__ sorted_score,
                                                    float* __restrict__ emb_feat,
                                                    unsigned short* __restrict__ embB,
                                                    float* __restrict__ sorted_boxes)
{
    const int b = blockIdx.x / C_, c = blockIdx.x % C_;
    __shared__ float p[NB_];
    __shared__ float wred[8];
    __shared__ int   sidxL[FN_];
    const int t = threadIdx.x;
    const int lane = t & 63, wv = t >> 6;

    // ---- softmax over 512 boxes (wave shfl + 8-slot combine)
    float s = scores[(size_t)(b*NB_ + t)*(C_+1) + c];
    float mx = s;
    #pragma unroll
    for (int o = 1; o < 64; o <<= 1) mx = fmaxf(mx, __shfl_xor(mx, o, 64));
    if (lane == 0) wred[wv] = mx;
    __syncthreads();
    mx = wred[0];
    #pragma unroll
    for (int j = 1; j < 8; ++j) mx = fmaxf(mx, wred[j]);
    float e = expf(s - mx);
    float ws_ = e;
    #pragma unroll
    for (int o = 1; o < 64; o <<= 1) ws_ += __shfl_xor(ws_, o, 64);
    __syncthreads();                 // wred reuse
    if (lane == 0) wred[wv] = ws_;
    __syncthreads();
    float sum = 0.f;
    #pragma unroll
    for (int j = 0; j < 8; ++j) sum += wred[j];
    float pi = e / sum;
    p[t] = pi;
    __syncthreads();

    // ---- stable descending rank
    int rank = 0;
    for (int j4 = 0; j4 < NB_/4; ++j4) {
        float4 pj = *(const float4*)&p[j4*4];
        int j = j4*4;
        rank += (pj.x > pi) || (pj.x == pi && (j+0) < t);
        rank += (pj.y > pi) || (pj.y == pi && (j+1) < t);
        rank += (pj.z > pi) || (pj.z == pi && (j+2) < t);
        rank += (pj.w > pi) || (pj.w == pi && (j+3) < t);
    }
    if (rank < FN_) {
        sidxL[rank] = t;
        sorted_score[(size_t)(b*FN_ + rank)*C_ + c] = pi;
    }
    __syncthreads();

    // ---- gather: 16 item-slots x 8 iters, 32 lanes/item (same pattern as old k_gather)
    {
        const int slot = t >> 5;
        const int l = t & 31;
        #pragma unroll
        for (int iter = 0; iter < 8; ++iter) {
            const int r = slot + 16*iter;        // item row 0..127
            const int idx = sidxL[r];
            const int row = b*NB_ + idx;
            float4 sm = make_float4(0.f, 0.f, 0.f, 0.f);
            #pragma unroll
            for (int kq = 0; kq < 4; ++kq) {
                float4 ev = *(const float4*)(roiP + (size_t)(kq*B_*NB_ + row)*FC_ + l*4);
                float4 rv = *(const float4*)(rankP + (size_t)(kq*FN_ + r)*FC_ + l*4);
                sm.x += ev.x + rv.x; sm.y += ev.y + rv.y;
                sm.z += ev.z + rv.z; sm.w += ev.w + rv.w;
            }
            const size_t itemoff = ((size_t)(b*FN_ + r)*C_ + c)*FC_;
            *(float4*)(emb_feat + itemoff + l*4) = sm;
            *(uint2*)(embB + itemoff + l*4) =
                make_uint2((unsigned)f2bf(sm.x) | ((unsigned)f2bf(sm.y) << 16),
                           (unsigned)f2bf(sm.z) | ((unsigned)f2bf(sm.w) << 16));
        }
    }
    // ---- refined boxes (threads 0..127, one item each)
    if (t < FN_) {
        const int r = t;
        const int idx = sidxL[r];
        const int row = b*NB_ + idx;
        float x1 = pboxes[row*4+0], y1 = pboxes[row*4+1], x2 = pboxes[row*4+2], y2 = pboxes[row*4+3];
        float w = x2 - x1, h = y2 - y1;
        float cx = x1 + 0.5f*w, cy = y1 + 0.5f*h;
        const float* dl = pdeltas + (size_t)row*(C_*4) + c*4;
        float dx = dl[0]/10.0f, dy = dl[1]/10.0f;
        float dw = fminf(dl[2]/5.0f, SCALE_CLAMP_);
        float dh = fminf(dl[3]/5.0f, SCALE_CLAMP_);
        float pcx = dx*w + cx, pcy = dy*h + cy;
        float pw = expf(dw)*w, ph = expf(dh)*h;
        const int item = (b*FN_ + r)*C_ + c;
        float* ob = sorted_boxes + (size_t)item*4;
        ob[0] = pcx - 0.5f*pw; ob[1] = pcy - 0.5f*ph;
        ob[2] = pcx + 0.5f*pw; ob[3] = pcy + 0.5f*ph;
    }
}

// ============ prior via MFMA -> store f16(log w) ============
__global__ __launch_bounds__(256) void k_pos2(const float* __restrict__ sorted_boxes,
                                              const float* __restrict__ pos_w,
                                              const float* __restrict__ pos_b,
                                              unsigned short* __restrict__ lw)
{
    const int n2   = blockIdx.x & 63;
    const int rest = blockIdx.x >> 6;
    const int cl   = rest % C_;
    const int b    = rest / C_;
    const int n0   = n2 * 2;
    const int t    = threadIdx.x;

    __shared__ float geomL[FN_][6];               // 3 KB
    __shared__ unsigned short featL[256*PE_];     // 32 KB, swizzled 128B rows
    __shared__ unsigned short poswL[G_*PE_];      // 2 KB, swizzled 128B rows
    __shared__ float pbL[G_];
    __shared__ float sdimL[8];

    if (t < FN_) {
        const float* bx = sorted_boxes + (((size_t)(b*FN_ + t))*C_ + cl)*4;
        float x1 = bx[0], y1 = bx[1], x2 = bx[2], y2 = bx[3];
        float w = x2 - x1 + 1.0f;
        float h = y2 - y1 + 1.0f;
        geomL[t][0] = 0.5f*(x1+x2);
        geomL[t][1] = 0.5f*(y1+y2);
        geomL[t][2] = w;
        geomL[t][3] = h;
        geomL[t][4] = __logf(w);
        geomL[t][5] = __logf(h);
    } else {
        int id = t - 128;
        int g  = id >> 3;
        int gr = id & 7;
        unsigned short u[8];
        #pragma unroll
        for (int j = 0; j < 8; ++j) u[j] = f2bf(pos_w[(gr*8 + j)*G_ + g]);
        *(uint4*)((char*)poswL + ADDR128(g, gr)) =
            make_uint4((unsigned)u[0] | ((unsigned)u[1] << 16),
                       (unsigned)u[2] | ((unsigned)u[3] << 16),
                       (unsigned)u[4] | ((unsigned)u[5] << 16),
                       (unsigned)u[6] | ((unsigned)u[7] << 16));
    }
    if (t < G_) pbL[t] = pos_b[t];
    if (t >= 16 && t < 24) sdimL[t-16] = 1.0f / powf(1000.0f, 0.125f*(float)(t-16));
    __syncthreads();

    {
        const int nl = t >> 7;
        const int m  = t & 127;
        const int n  = n0 + nl;
        float pm[4];
        {
            float cxn = geomL[n][0], cyn = geomL[n][1];
            float rwn = 1.0f/geomL[n][2], rhn = 1.0f/geomL[n][3];
            pm[0] = __logf(fmaxf(fabsf((cxn - geomL[m][0]) * rwn), 1e-3f)) * 100.0f;
            pm[1] = __logf(fmaxf(fabsf((cyn - geomL[m][1]) * rhn), 1e-3f)) * 100.0f;
            pm[2] = (geomL[n][4] - geomL[m][4]) * 100.0f;
            pm[3] = (geomL[n][5] - geomL[m][5]) * 100.0f;
        }
        char* base = (char*)featL;
        #pragma unroll
        for (int f = 0; f < 4; ++f) {
            float s[8], c[8];
            #pragma unroll
            for (int r = 0; r < 8; ++r) {
                __sincosf(pm[f] * sdimL[r], &s[r], &c[r]);
            }
            unsigned short us[8], uc[8];
            #pragma unroll
            for (int r = 0; r < 8; ++r) { us[r] = f2bf(s[r]); uc[r] = f2bf(c[r]); }
            *(uint4*)(base + ADDR128(t, 2*f)) =
                make_uint4((unsigned)us[0] | ((unsigned)us[1] << 16),
                           (unsigned)us[2] | ((unsigned)us[3] << 16),
                           (unsigned)us[4] | ((unsigned)us[5] << 16),
                           (unsigned)us[6] | ((unsigned)us[7] << 16));
            *(uint4*)(base + ADDR128(t, 2*f + 1)) =
                make_uint4((unsigned)uc[0] | ((unsigned)uc[1] << 16),
                           (unsigned)uc[2] | ((unsigned)uc[3] << 16),
                           (unsigned)uc[4] | ((unsigned)uc[5] << 16),
                           (unsigned)uc[6] | ((unsigned)uc[7] << 16));
        }
    }
    __syncthreads();

    {
        const int wave = t >> 6, lane = t & 63;
        const int lr = lane & 15, lh = lane >> 4;
        const float pbg = pbL[lr];           // g = lr
        #pragma unroll
        for (int ti = 0; ti < 4; ++ti) {
            const int t16 = wave*4 + ti;
            f32x4 acc = {0,0,0,0};
            #pragma unroll
            for (int ks = 0; ks < 2; ++ks) {
                bf16x8 a  = *(const bf16x8*)((char*)featL + ADDR128(t16*16 + lr, ks*4 + lh));
                bf16x8 bb = *(const bf16x8*)((char*)poswL + ADDR128(lr, ks*4 + lh));
                acc = __builtin_amdgcn_mfma_f32_16x16x32_bf16(a, bb, acc, 0, 0, 0);
            }
            const int g = lr;
            #pragma unroll
            for (int reg = 0; reg < 4; ++reg) {
                int p = t16*16 + lh*4 + reg;
                int n = n0 + (p >> 7);
                int m = p & 127;
                float w = fmaxf(fmaxf(acc[reg] + pbg, 0.0f), 1e-6f);
                lw[(((size_t)(b*C_ + cl)*FN_ + n)*G_ + g)*FN_ + m] = f2h(__logf(w));
            }
        }
    }
}

// ============ MFMA attention per (batch, class, group) — 70.5 KB LDS ============
// region FT (34816 B, rows stride 272B): ft bf16 -> aff f16 -> P bf16
#define FT_OFF   0
#define QL_OFF   34816    // q bf16 [128n][64dq] swz 16 KB
#define KL_OFF   51200    // k bf16 [128m][64dq] swz 16 KB
#define VT_OFF   67584    // V'^T bf16 [16e][128m] swz 4 KB
#define BIAS_OFF 71680    // 128 f32
#define SMEM_SZ  72192

__global__ __launch_bounds__(1024, 8) void k_attn(const unsigned short* __restrict__ embB,
                                               const unsigned short* __restrict__ wt,
                                               const float* __restrict__ q_b,
                                               const float* __restrict__ k_b,
                                               const float* __restrict__ out_b,
                                               const unsigned short* __restrict__ lw,
                                               float* __restrict__ att)
{
    const int g    = blockIdx.x & 15;
    const int rest = blockIdx.x >> 4;
    const int cl   = rest % C_;
    const int b    = rest / C_;
    const int c    = cl;
    const int t  = threadIdx.x;
    const int wave = t >> 6;
    const int lane = t & 63;
    const int lr = lane & 15;
    const int lh = lane >> 4;              // 0..3

    __shared__ char smem[SMEM_SZ];
    float* biasL = (float*)(smem + BIAS_OFF);

    // ================= P0: staging (ft copy bf16 + VT-zero + bias) =================
    {
        const char* src = (const char*)embB + ((size_t)(b*FN_)*C_ + c)*FC_*2;
        #pragma unroll
        for (int s = 0; s < 2; ++s) {
            int fi = t + s*1024;
            int n  = fi >> 4;
            int o16 = (fi & 15) * 16;
            uint4 v = *(const uint4*)(src + (size_t)n*C_*FC_*2 + o16);
            *(uint4*)(smem + FT_OFF + n*272 + o16) = v;
        }
    }
    if (t >= 512 && t < 768) {
        int i = t - 512;
        *(uint2*)(smem + VT_OFF + 8*256 + i*8) = make_uint2(0u, 0u);
    }
    if (t >= 128 && t < 256) {
        int r = t - 128;
        biasL[r] = (r < 64) ? q_b[g*DQ_ + r] : k_b[g*DQ_ + (r-64)];
    }
    __syncthreads();

    // ================= P1: proj MFMA (A from pre-transposed bf16 WT) =================
    {
        const int rb = (wave >> 2) * 32;
        const int nb = (wave & 3) * 32;
        const char* wtg = (const char*)wt + (size_t)g*144*256;
        f32x4 acc00 = {0,0,0,0}, acc01 = {0,0,0,0}, acc10 = {0,0,0,0}, acc11 = {0,0,0,0};
        f32x4 accV  = {0,0,0,0};
        #pragma unroll
        for (int ks = 0; ks < 4; ++ks) {
            const int fo = ks*64 + lh*16;
            bf16x8 a0 = *(const bf16x8*)(wtg + (rb + lr)*256 + fo);
            bf16x8 a1 = *(const bf16x8*)(wtg + (rb + 16 + lr)*256 + fo);
            bf16x8 b0 = *(const bf16x8*)(smem + FT_OFF + (nb + lr)*272 + fo);
            bf16x8 b1 = *(const bf16x8*)(smem + FT_OFF + (nb + 16 + lr)*272 + fo);
            acc00 = __builtin_amdgcn_mfma_f32_16x16x32_bf16(a0, b0, acc00, 0, 0, 0);
            acc01 = __builtin_amdgcn_mfma_f32_16x16x32_bf16(a0, b1, acc01, 0, 0, 0);
            acc10 = __builtin_amdgcn_mfma_f32_16x16x32_bf16(a1, b0, acc10, 0, 0, 0);
            acc11 = __builtin_amdgcn_mfma_f32_16x16x32_bf16(a1, b1, acc11, 0, 0, 0);
            if (wave < 8) {
                bf16x8 av = *(const bf16x8*)(wtg + (128 + lr)*256 + fo);
                bf16x8 bv = *(const bf16x8*)(smem + FT_OFF + (wave*16 + lr)*272 + fo);
                accV = __builtin_amdgcn_mfma_f32_16x16x32_bf16(av, bv, accV, 0, 0, 0);
            }
        }
        #pragma unroll
        for (int ti = 0; ti < 2; ++ti) {
            #pragma unroll
            for (int tj = 0; tj < 2; ++tj) {
                f32x4 a = (ti == 0) ? (tj == 0 ? acc00 : acc01) : (tj == 0 ? acc10 : acc11);
                int r0 = rb + ti*16 + lh*4;
                int n  = nb + tj*16 + lr;
                float v0 = a[0] + biasL[r0+0];
                float v1 = a[1] + biasL[r0+1];
                float v2 = a[2] + biasL[r0+2];
                float v3 = a[3] + biasL[r0+3];
                int dq0 = r0 & 63;
                int off = (r0 < 64 ? QL_OFF : KL_OFF);
                char* dst = smem + off + ADDR128(n, dq0 >> 3) + ((dq0 >> 2) & 1)*8;
                *(uint2*)dst = make_uint2((unsigned)f2bf(v0) | ((unsigned)f2bf(v1) << 16),
                                          (unsigned)f2bf(v2) | ((unsigned)f2bf(v3) << 16));
            }
        }
        if (wave < 8 && lh < 2) {
            int m = wave*16 + lr;
            #pragma unroll
            for (int reg = 0; reg < 4; ++reg) {
                int e = lh*4 + reg;
                char* dst = smem + VT_OFF + (e)*256 + ((((m >> 3) ^ e)) << 4) + (m & 7)*2;
                *(unsigned short*)dst = f2bf(accV[reg]);
            }
        }
    }
    __syncthreads();

    // ================= P2: issue lw loads (T14 async-split), then aff MFMA -> f16 =================
    uint4 gl0, gl1;
    {
        const int row_p = t >> 3;
        const int lp_p  = t & 7;
        const unsigned short* lwrow = lw + ((((size_t)(b*C_ + cl))*FN_ + row_p)*G_ + g)*FN_ + lp_p*16;
        gl0 = *(const uint4*)(lwrow);
        gl1 = *(const uint4*)(lwrow + 8);
    }
    {
        const int nb = (wave >> 2) * 32;
        const int mb = (wave & 3) * 32;
        f32x4 acc00 = {0,0,0,0}, acc01 = {0,0,0,0}, acc10 = {0,0,0,0}, acc11 = {0,0,0,0};
        #pragma unroll
        for (int ks = 0; ks < 2; ++ks) {
            int soff = ((ks*4 + lh) ^ (lr & 7)) << 4;
            bf16x8 a0 = *(const bf16x8*)(smem + QL_OFF + (nb + lr)*128 + soff);
            bf16x8 a1 = *(const bf16x8*)(smem + QL_OFF + (nb + 16 + lr)*128 + soff);
            bf16x8 b0 = *(const bf16x8*)(smem + KL_OFF + (mb + lr)*128 + soff);
            bf16x8 b1 = *(const bf16x8*)(smem + KL_OFF + (mb + 16 + lr)*128 + soff);
            acc00 = __builtin_amdgcn_mfma_f32_16x16x32_bf16(a0, b0, acc00, 0, 0, 0);
            acc01 = __builtin_amdgcn_mfma_f32_16x16x32_bf16(a0, b1, acc01, 0, 0, 0);
            acc10 = __builtin_amdgcn_mfma_f32_16x16x32_bf16(a1, b0, acc10, 0, 0, 0);
            acc11 = __builtin_amdgcn_mfma_f32_16x16x32_bf16(a1, b1, acc11, 0, 0, 0);
        }
        #pragma unroll
        for (int ti = 0; ti < 2; ++ti) {
            #pragma unroll
            for (int tj = 0; tj < 2; ++tj) {
                f32x4 a = (ti == 0) ? (tj == 0 ? acc00 : acc01) : (tj == 0 ? acc10 : acc11);
                int n0 = nb + ti*16 + lh*4;
                int m  = mb + tj*16 + lr;
                #pragma unroll
                for (int reg = 0; reg < 4; ++reg)
                    *(unsigned short*)(smem + FT_OFF + (n0 + reg)*272 + 2*m) = f2h(a[reg]);
            }
        }
    }
    __syncthreads();

    // ================= P3: softmax (aff f16 LDS + prefetched lw regs) -> P bf16 in place =================
    {
        const int row = t >> 3;
        const int lp  = t & 7;
        char* abase = smem + FT_OFF + row*272 + lp*32;
        uint4 af0 = *(const uint4*)abase;
        uint4 af1 = *(const uint4*)(abase + 16);
        const unsigned short* ah0 = (const unsigned short*)&af0;
        const unsigned short* ah1 = (const unsigned short*)&af1;
        const unsigned short* lp0 = (const unsigned short*)&gl0;
        const unsigned short* lp1 = (const unsigned short*)&gl1;
        float v[16];
        float mx = -INFINITY;
        #pragma unroll
        for (int j = 0; j < 8; ++j) {
            float val = h2f(ah0[j])*0.125f + h2f(lp0[j]);
            v[j] = val; mx = fmaxf(mx, val);
        }
        #pragma unroll
        for (int j = 0; j < 8; ++j) {
            float val = h2f(ah1[j])*0.125f + h2f(lp1[j]);
            v[8+j] = val; mx = fmaxf(mx, val);
        }
        #pragma unroll
        for (int s = 1; s < 8; s <<= 1) mx = fmaxf(mx, __shfl_xor(mx, s, 8));
        float sum = 0.f;
        #pragma unroll
        for (int j = 0; j < 16; ++j) { v[j] = __expf(v[j] - mx); sum += v[j]; }
        #pragma unroll
        for (int s = 1; s < 8; s <<= 1) sum += __shfl_xor(sum, s, 8);
        float rs = 1.0f / sum;
        unsigned short u[16];
        #pragma unroll
        for (int j = 0; j < 16; ++j) u[j] = f2bf(v[j] * rs);
        *(uint4*)abase = make_uint4((unsigned)u[0] | ((unsigned)u[1] << 16),
                                    (unsigned)u[2] | ((unsigned)u[3] << 16),
                                    (unsigned)u[4] | ((unsigned)u[5] << 16),
                                    (unsigned)u[6] | ((unsigned)u[7] << 16));
        *(uint4*)(abase + 16) = make_uint4((unsigned)u[8]  | ((unsigned)u[9]  << 16),
                                           (unsigned)u[10] | ((unsigned)u[11] << 16),
                                           (unsigned)u[12] | ((unsigned)u[13] << 16),
                                           (unsigned)u[14] | ((unsigned)u[15] << 16));
    }
    __syncthreads();

    // ================= P4: att = P @ V' =================
    if (wave < 8) {
        const int tb = wave * 16;
        f32x4 acc = {0,0,0,0};
        #pragma unroll
        for (int ks = 0; ks < 4; ++ks) {
            const int fo = ks*64 + lh*16;
            int soff = ((ks*4 + lh) ^ lr) << 4;
            bf16x8 a = *(const bf16x8*)(smem + FT_OFF + (tb + lr)*272 + fo);
            bf16x8 bv = *(const bf16x8*)(smem + VT_OFF + lr*256 + soff);
            acc = __builtin_amdgcn_mfma_f32_16x16x32_bf16(a, bv, acc, 0, 0, 0);
        }
        if (lr < 8) {
            float ob = out_b[g*EO_ + lr];
            #pragma unroll
            for (int reg = 0; reg < 4; ++reg) {
                int n = tb + lh*4 + reg;
                att[((size_t)(b*FN_ + n)*C_ + c)*FC_ + g*EO_ + lr] = acc[reg] + ob;
            }
        }
    }
}

// ============ final: 8 items/block, 32 lanes/item ============
__global__ __launch_bounds__(256) void k_final(const float* __restrict__ emb_feat,
                                               const float* __restrict__ att,
                                               const float* __restrict__ logit_w,
                                               const float* __restrict__ logit_b,
                                               const float* __restrict__ sorted_score,
                                               float* __restrict__ out)
{
    __shared__ float lwL[FC_*NT_ + NT_];
    const int t = threadIdx.x;
    for (int i = t; i < FC_*NT_ + NT_; i += 256)
        lwL[i] = (i < FC_*NT_) ? logit_w[i] : logit_b[i - FC_*NT_];
    __syncthreads();
    const int item = blockIdx.x*8 + (t >> 5);
    const int l = t & 31;
    const int d0 = l*4;
    float4 ev = *(const float4*)(emb_feat + (size_t)item*FC_ + d0);
    float4 av = *(const float4*)(att + (size_t)item*FC_ + d0);
    float a0 = fmaxf(ev.x + av.x, 0.f);
    float a1 = fmaxf(ev.y + av.y, 0.f);
    float a2 = fmaxf(ev.z + av.z, 0.f);
    float a3 = fmaxf(ev.w + av.w, 0.f);
    float s0 = a0*lwL[(d0+0)*NT_+0] + a1*lwL[(d0+1)*NT_+0] + a2*lwL[(d0+2)*NT_+0] + a3*lwL[(d0+3)*NT_+0];
    float s1 = a0*lwL[(d0+0)*NT_+1] + a1*lwL[(d0+1)*NT_+1] + a2*lwL[(d0+2)*NT_+1] + a3*lwL[(d0+3)*NT_+1];
    float s2 = a0*lwL[(d0+0)*NT_+2] + a1*lwL[(d0+1)*NT_+2] + a2*lwL[(d0+2)*NT_+2] + a3*lwL[(d0+3)*NT_+2];
    #pragma unroll
    for (int s = 1; s < 32; s <<= 1) {
        s0 += __shfl_xor(s0, s, 32);
        s1 += __shfl_xor(s1, s, 32);
        s2 += __shfl_xor(s2, s, 32);
    }
    if (l < NT_) {
        float lg = (l == 0) ? s0 : (l == 1) ? s1 : s2;
        lg += lwL[FC_*NT_ + l];
        float sg = 1.f / (1.f + expf(-lg));
        out[(size_t)item*NT_ + l] = sg * sorted_score[item];
    }
}

extern "C" void kernel_launch(void* const* d_in, const int* in_sizes, int n_in,
                              void* d_out, int out_size, void* d_ws, size_t ws_size,
                              hipStream_t stream) {
    (void)in_sizes; (void)n_in; (void)out_size; (void)ws_size;
    const float* roi_feat = (const float*)d_in[0];
    const float* scores   = (const float*)d_in[1];
    const float* pdeltas  = (const float*)d_in[2];
    const float* pboxes   = (const float*)d_in[3];
    const float* roi_w    = (const float*)d_in[4];
    const float* roi_b    = (const float*)d_in[5];
    const float* rank_w   = (const float*)d_in[6];
    const float* rank_b   = (const float*)d_in[7];
    const float* logit_w  = (const float*)d_in[8];
    const float* logit_b  = (const float*)d_in[9];
    const float* pos_w    = (const float*)d_in[10];
    const float* pos_b    = (const float*)d_in[11];
    const float* q_w      = (const float*)d_in[12];
    const float* q_b      = (const float*)d_in[13];
    const float* k_w      = (const float*)d_in[14];
    const float* k_b      = (const float*)d_in[15];
    const float* out_w    = (const float*)d_in[16];
    const float* out_b    = (const float*)d_in[17];
    float* ws = (float*)d_ws;

    float* roiP         = ws + O_ROIP;
    float* rankP        = ws + O_RANKP;
    float* sorted_score = ws + O_SSCORE;
    float* sorted_boxes = ws + O_SBOX;
    float* emb_feat     = ws + O_EMB;
    float* att          = ws + O_ATT;
    unsigned short* lwb = (unsigned short*)(ws + O_LW);
    unsigned short* wtb = (unsigned short*)(ws + O_WT);
    unsigned short* embB = (unsigned short*)(ws + O_EMBB);

    k_embed<<<dim3(304), dim3(256), 0, stream>>>(roi_feat, roi_w, roi_b, rank_w, rank_b,
                                                 q_w, k_w, out_w, roiP, rankP, wtb);
    k_topkgather<<<dim3(B_*C_), dim3(512), 0, stream>>>(scores, roiP, rankP, pdeltas, pboxes,
                                                        sorted_score, emb_feat, embB, sorted_boxes);
    k_pos2<<<dim3(B_*C_*64), dim3(256), 0, stream>>>(sorted_boxes, pos_w, pos_b, lwb);
    k_attn<<<dim3(B_*C_*G_), dim3(1024), 0, stream>>>(embB, wtb, q_b, k_b, out_b, lwb, att);
    k_final<<<dim3(B_*FN_*C_/8), dim3(256), 0, stream>>>(emb_feat, att, logit_w, logit_b,
                                                         sorted_score, d_out ? (float*)d_out : nullptr);
}